// Round 1
// baseline (993.158 us; speedup 1.0000x reference)
//
#include <hip/hip_runtime.h>
#include <math.h>

#define NN 50000
#define EE 500000
#define HH 128
#define NHEADS 3
#define CC 10
#define GG 64
#define EPSV 1e-5f
#define SLOPE 0.2f

// ---------------- CSR build ----------------

__global__ void k_count_deg(const int* __restrict__ ei, int* __restrict__ deg) {
    int e = blockIdx.x * 256 + threadIdx.x;
    if (e < EE) atomicAdd(&deg[ei[EE + e]], 1);
}

__global__ void k_scan1(const int* __restrict__ deg, int* __restrict__ row_start,
                        int* __restrict__ blk) {
    __shared__ int s[256];
    int i = blockIdx.x * 256 + threadIdx.x;
    int v = (i < NN) ? deg[i] : 0;
    s[threadIdx.x] = v;
    __syncthreads();
    for (int o = 1; o < 256; o <<= 1) {
        int t = (threadIdx.x >= o) ? s[threadIdx.x - o] : 0;
        __syncthreads();
        s[threadIdx.x] += t;
        __syncthreads();
    }
    if (i < NN) row_start[i] = s[threadIdx.x] - v;  // exclusive
    if (threadIdx.x == 255) blk[blockIdx.x] = s[255];
}

__global__ void k_scan2(int* __restrict__ blk, int nb) {
    __shared__ int s[256];
    int v = (threadIdx.x < nb) ? blk[threadIdx.x] : 0;
    s[threadIdx.x] = v;
    __syncthreads();
    for (int o = 1; o < 256; o <<= 1) {
        int t = (threadIdx.x >= o) ? s[threadIdx.x - o] : 0;
        __syncthreads();
        s[threadIdx.x] += t;
        __syncthreads();
    }
    if (threadIdx.x < nb) blk[threadIdx.x] = s[threadIdx.x] - v;  // exclusive
}

__global__ void k_scan3(int* __restrict__ row_start, const int* __restrict__ blk,
                        const int* __restrict__ deg, int* __restrict__ cursor,
                        float* __restrict__ dinv, float* __restrict__ inv_sage) {
    int i = blockIdx.x * 256 + threadIdx.x;
    if (i < NN) {
        int rs = row_start[i] + blk[blockIdx.x];
        row_start[i] = rs;
        cursor[i] = rs;
        int d = deg[i];
        dinv[i] = rsqrtf((float)(d + 1));
        inv_sage[i] = 1.0f / (float)(d > 1 ? d : 1);
    }
}

__global__ void k_fill(const int* __restrict__ ei, int* __restrict__ cursor,
                       int* __restrict__ csr_src) {
    int e = blockIdx.x * 256 + threadIdx.x;
    if (e < EE) {
        int d = ei[EE + e];
        int p = atomicAdd(&cursor[d], 1);
        csr_src[p] = ei[e];
    }
}

// ---------------- GEMM (fp32, K=128, BM=BN=64, 256 threads) ----------------

template <bool ACC, bool BIAS>
__global__ __launch_bounds__(256) void k_gemm(const float* __restrict__ A,
                                              const float* __restrict__ B,
                                              const float* __restrict__ bias,
                                              float* __restrict__ C, int M, int Nn) {
    __shared__ float AsT[128 * 68];  // [k][r], stride 68
    __shared__ float Bs[128 * 64];   // [k][c]
    int tid = threadIdx.x;
    int rBase = blockIdx.x * 64, cBase = blockIdx.y * 64;

#pragma unroll
    for (int q = 0; q < 8; q++) {
        int slot = q * 256 + tid;
        int r = slot >> 5, k4 = slot & 31;
        float4 v = make_float4(0.f, 0.f, 0.f, 0.f);
        int gr = rBase + r;
        if (gr < M) v = *(const float4*)(A + (size_t)gr * 128 + k4 * 4);
        AsT[(k4 * 4 + 0) * 68 + r] = v.x;
        AsT[(k4 * 4 + 1) * 68 + r] = v.y;
        AsT[(k4 * 4 + 2) * 68 + r] = v.z;
        AsT[(k4 * 4 + 3) * 68 + r] = v.w;
    }
#pragma unroll
    for (int q = 0; q < 8; q++) {
        int slot = q * 256 + tid;
        int k = slot >> 4, c4 = slot & 15;
        *(float4*)(Bs + k * 64 + c4 * 4) = *(const float4*)(B + (size_t)k * Nn + cBase + c4 * 4);
    }
    __syncthreads();

    int tr = tid >> 4, tc = tid & 15;
    float acc[4][4];
#pragma unroll
    for (int i = 0; i < 4; i++)
#pragma unroll
        for (int j = 0; j < 4; j++) acc[i][j] = 0.f;

#pragma unroll 8
    for (int k = 0; k < 128; k++) {
        float4 a = *(const float4*)(AsT + k * 68 + tr * 4);
        float4 b = *(const float4*)(Bs + k * 64 + tc * 4);
        acc[0][0] += a.x * b.x; acc[0][1] += a.x * b.y; acc[0][2] += a.x * b.z; acc[0][3] += a.x * b.w;
        acc[1][0] += a.y * b.x; acc[1][1] += a.y * b.y; acc[1][2] += a.y * b.z; acc[1][3] += a.y * b.w;
        acc[2][0] += a.z * b.x; acc[2][1] += a.z * b.y; acc[2][2] += a.z * b.z; acc[2][3] += a.z * b.w;
        acc[3][0] += a.w * b.x; acc[3][1] += a.w * b.y; acc[3][2] += a.w * b.z; acc[3][3] += a.w * b.w;
    }

#pragma unroll
    for (int i = 0; i < 4; i++) {
        int r = rBase + tr * 4 + i;
        if (r < M) {
            float4 o = make_float4(acc[i][0], acc[i][1], acc[i][2], acc[i][3]);
            size_t cidx = (size_t)r * Nn + cBase + tc * 4;
            if (BIAS) {
                float4 bb = *(const float4*)(bias + cBase + tc * 4);
                o.x += bb.x; o.y += bb.y; o.z += bb.z; o.w += bb.w;
            }
            if (ACC) {
                float4 cc = *(const float4*)(C + cidx);
                o.x += cc.x; o.y += cc.y; o.z += cc.z; o.w += cc.w;
            }
            *(float4*)(C + cidx) = o;
        }
    }
}

// ---------------- Aggregations (1 wave per node) ----------------

__global__ void k_gcn_agg(const float* __restrict__ h, const int* __restrict__ row_start,
                          const int* __restrict__ deg, const int* __restrict__ csr,
                          const float* __restrict__ dinv, const float* __restrict__ b1,
                          float* __restrict__ out) {
    int n = blockIdx.x * 4 + (threadIdx.x >> 6);
    if (n >= NN) return;
    int lane = threadIdx.x & 63;
    const float2* hp = (const float2*)h;
    float di = dinv[n];
    float2 hv = hp[(size_t)n * 64 + lane];
    float ws = di * di;
    float2 acc;
    acc.x = hv.x * ws;
    acc.y = hv.y * ws;
    int s0 = row_start[n], cnt = deg[n];
    for (int i = 0; i < cnt; i++) {
        int s = csr[s0 + i];
        float w = dinv[s] * di;
        float2 v = hp[(size_t)s * 64 + lane];
        acc.x += v.x * w;
        acc.y += v.y * w;
    }
    float2 bb = ((const float2*)b1)[lane];
    acc.x += bb.x;
    acc.y += bb.y;
    ((float2*)out)[(size_t)n * 64 + lane] = acc;
}

__global__ void k_sage_agg(const float* __restrict__ h, const int* __restrict__ row_start,
                           const int* __restrict__ deg, const int* __restrict__ csr,
                           const float* __restrict__ inv_sage, float* __restrict__ out) {
    int n = blockIdx.x * 4 + (threadIdx.x >> 6);
    if (n >= NN) return;
    int lane = threadIdx.x & 63;
    const float2* hp = (const float2*)h;
    float2 acc = make_float2(0.f, 0.f);
    int s0 = row_start[n], cnt = deg[n];
    for (int i = 0; i < cnt; i++) {
        int s = csr[s0 + i];
        float2 v = hp[(size_t)s * 64 + lane];
        acc.x += v.x;
        acc.y += v.y;
    }
    float sc = inv_sage[n];
    acc.x *= sc;
    acc.y *= sc;
    ((float2*)out)[(size_t)n * 64 + lane] = acc;
}

__global__ void k_att(const float* __restrict__ h3, const float* __restrict__ att_src,
                      const float* __restrict__ att_dst, float* __restrict__ asrc,
                      float* __restrict__ adst) {
    int n = blockIdx.x * 4 + (threadIdx.x >> 6);
    if (n >= NN) return;
    int lane = threadIdx.x & 63;
    const float* row = h3 + (size_t)n * 384;
#pragma unroll
    for (int hd = 0; hd < 3; hd++) {
        float v0 = row[hd * 128 + lane];
        float v1 = row[hd * 128 + 64 + lane];
        float s1 = v0 * att_src[hd * 128 + lane] + v1 * att_src[hd * 128 + 64 + lane];
        float s2 = v0 * att_dst[hd * 128 + lane] + v1 * att_dst[hd * 128 + 64 + lane];
        for (int o = 32; o > 0; o >>= 1) {
            s1 += __shfl_down(s1, o, 64);
            s2 += __shfl_down(s2, o, 64);
        }
        if (lane == 0) {
            asrc[n * 3 + hd] = s1;
            adst[n * 3 + hd] = s2;
        }
    }
}

__device__ __forceinline__ float lrelu(float a) { return fmaxf(a, SLOPE * a); }

__global__ void k_gat_agg(const float* __restrict__ h3, const int* __restrict__ row_start,
                          const int* __restrict__ deg, const int* __restrict__ csr,
                          const float* __restrict__ asrc, const float* __restrict__ adst,
                          const float* __restrict__ b3, float* __restrict__ out) {
    int n = blockIdx.x * 4 + (threadIdx.x >> 6);
    if (n >= NN) return;
    int lane = threadIdx.x & 63;
    const float2* hp = (const float2*)h3;  // row stride = 192 float2
    float ad0 = adst[n * 3 + 0], ad1 = adst[n * 3 + 1], ad2 = adst[n * 3 + 2];
    // self loop
    float m0 = lrelu(asrc[n * 3 + 0] + ad0);
    float m1 = lrelu(asrc[n * 3 + 1] + ad1);
    float m2 = lrelu(asrc[n * 3 + 2] + ad2);
    float l0 = 1.f, l1 = 1.f, l2 = 1.f;
    size_t base = (size_t)n * 192;
    float2 a0 = hp[base + 0 + lane];
    float2 a1 = hp[base + 64 + lane];
    float2 a2 = hp[base + 128 + lane];
    int s0r = row_start[n], cnt = deg[n];
    for (int i = 0; i < cnt; i++) {
        int s = csr[s0r + i];
        float e0 = lrelu(asrc[s * 3 + 0] + ad0);
        float e1 = lrelu(asrc[s * 3 + 1] + ad1);
        float e2 = lrelu(asrc[s * 3 + 2] + ad2);
        size_t sb = (size_t)s * 192;
        float2 v0 = hp[sb + 0 + lane];
        float2 v1 = hp[sb + 64 + lane];
        float2 v2 = hp[sb + 128 + lane];
        float mn, sc, w;
        mn = fmaxf(m0, e0); sc = __expf(m0 - mn); w = __expf(e0 - mn);
        l0 = l0 * sc + w; a0.x = a0.x * sc + w * v0.x; a0.y = a0.y * sc + w * v0.y; m0 = mn;
        mn = fmaxf(m1, e1); sc = __expf(m1 - mn); w = __expf(e1 - mn);
        l1 = l1 * sc + w; a1.x = a1.x * sc + w * v1.x; a1.y = a1.y * sc + w * v1.y; m1 = mn;
        mn = fmaxf(m2, e2); sc = __expf(m2 - mn); w = __expf(e2 - mn);
        l2 = l2 * sc + w; a2.x = a2.x * sc + w * v2.x; a2.y = a2.y * sc + w * v2.y; m2 = mn;
    }
    float r0 = 1.f / l0, r1 = 1.f / l1, r2 = 1.f / l2;
    float2 bb = ((const float2*)b3)[lane];
    float2 o;
    o.x = (a0.x * r0 + a1.x * r1 + a2.x * r2) * (1.f / 3.f) + bb.x;
    o.y = (a0.y * r0 + a1.y * r1 + a2.y * r2) * (1.f / 3.f) + bb.y;
    ((float2*)out)[(size_t)n * 64 + lane] = o;
}

// ---------------- BatchNorm + ELU ----------------

__global__ void k_bn_stats(const float* __restrict__ h, float* __restrict__ sums) {
    int f = threadIdx.x;  // 128 threads
    int rows_per = (NN + gridDim.x - 1) / gridDim.x;
    int r0 = blockIdx.x * rows_per;
    int r1 = r0 + rows_per;
    if (r1 > NN) r1 = NN;
    float s = 0.f, sq = 0.f;
    for (int r = r0; r < r1; r++) {
        float v = h[(size_t)r * 128 + f];
        s += v;
        sq += v * v;
    }
    atomicAdd(&sums[f], s);
    atomicAdd(&sums[128 + f], sq);
}

__global__ void k_bn_fin(const float* __restrict__ sums, const float* __restrict__ gamma,
                         const float* __restrict__ beta, float* __restrict__ coef) {
    int f = threadIdx.x;
    float mu = sums[f] * (1.0f / NN);
    float var = sums[128 + f] * (1.0f / NN) - mu * mu;
    float rs = rsqrtf(var + EPSV);
    float sc = rs * gamma[f];
    coef[f] = sc;
    coef[128 + f] = beta[f] - mu * sc;
}

__device__ __forceinline__ float elu1(float x) { return x > 0.f ? x : (__expf(x) - 1.f); }

__global__ void k_bn_elu(float* __restrict__ h, const float* __restrict__ coef) {
    int i = blockIdx.x * 256 + threadIdx.x;
    if (i >= NN * 32) return;
    int f4 = (i & 31) << 2;
    float4 v = ((float4*)h)[i];
    float4 sc = *(const float4*)(coef + f4);
    float4 sh = *(const float4*)(coef + 128 + f4);
    v.x = elu1(v.x * sc.x + sh.x);
    v.y = elu1(v.y * sc.y + sh.y);
    v.z = elu1(v.z * sc.z + sh.z);
    v.w = elu1(v.w * sc.w + sh.w);
    ((float4*)h)[i] = v;
}

// ---------------- Pool + classifier ----------------

__global__ void k_pool(const float* __restrict__ h, const int* __restrict__ batch,
                       float* __restrict__ out) {
    int g = blockIdx.x;
    int f = threadIdx.x;  // 128
    int lo = 0, hi = NN;
    while (lo < hi) { int mid = (lo + hi) >> 1; if (batch[mid] < g) lo = mid + 1; else hi = mid; }
    int start = lo;
    hi = NN;
    while (lo < hi) { int mid = (lo + hi) >> 1; if (batch[mid] < g + 1) lo = mid + 1; else hi = mid; }
    int end = lo;
    float s = 0.f;
    for (int r = start; r < end; r++) s += h[(size_t)r * 128 + f];
    int c = end - start;
    out[g * 128 + f] = s / (float)(c > 1 ? c : 1);
}

__global__ void k_logits(const float* __restrict__ pooled, const float* __restrict__ Wc,
                         const float* __restrict__ bc, float* __restrict__ out) {
    int i = blockIdx.x * 256 + threadIdx.x;
    if (i >= GG * CC) return;
    int g = i / CC, c = i % CC;
    float s = bc[c];
    for (int k = 0; k < 128; k++) s += pooled[g * 128 + k] * Wc[k * CC + c];
    out[i] = s;
}

// ---------------- launch ----------------

extern "C" void kernel_launch(void* const* d_in, const int* in_sizes, int n_in,
                              void* d_out, int out_size, void* d_ws, size_t ws_size,
                              hipStream_t stream) {
    const float* x = (const float*)d_in[0];
    const int* ei = (const int*)d_in[1];
    const int* batch = (const int*)d_in[2];
    const float* W1 = (const float*)d_in[3];
    const float* b1 = (const float*)d_in[4];
    const float* gamma1 = (const float*)d_in[5];
    const float* beta1 = (const float*)d_in[6];
    const float* Wl = (const float*)d_in[7];
    const float* bl = (const float*)d_in[8];
    const float* Wr = (const float*)d_in[9];
    const float* gamma2 = (const float*)d_in[10];
    const float* beta2 = (const float*)d_in[11];
    const float* W3 = (const float*)d_in[12];
    const float* att_src = (const float*)d_in[13];
    const float* att_dst = (const float*)d_in[14];
    const float* b3 = (const float*)d_in[15];
    const float* gamma3 = (const float*)d_in[16];
    const float* beta3 = (const float*)d_in[17];
    const float* Wc = (const float*)d_in[18];
    const float* bc = (const float*)d_in[19];

    char* w = (char*)d_ws;
    const size_t SZ_NH = (size_t)NN * 128 * 4;  // 25.6 MB
    float* bufA = (float*)(w + 0);
    float* bufB = (float*)(w + SZ_NH);
    float* bufC = (float*)(w + 2 * SZ_NH);
    float* buf3 = (float*)(w + 3 * SZ_NH);            // N x 384
    size_t o = 3 * SZ_NH + (size_t)NN * 384 * 4;      // 153.6 MB
    int* csr = (int*)(w + o); o += (size_t)EE * 4;
    int* deg = (int*)(w + o); o += (size_t)NN * 4;
    int* row_start = (int*)(w + o); o += (size_t)NN * 4;
    int* cursor = (int*)(w + o); o += (size_t)NN * 4;
    float* dinv = (float*)(w + o); o += (size_t)NN * 4;
    float* inv_sage = (float*)(w + o); o += (size_t)NN * 4;
    float* asrc = (float*)(w + o); o += (size_t)NN * 3 * 4;
    float* adst = (float*)(w + o); o += (size_t)NN * 3 * 4;
    float* bn_sums = (float*)(w + o); o += 3 * 256 * 4;
    float* bn_coef = (float*)(w + o); o += 256 * 4;
    int* blk = (int*)(w + o); o += 1024;

    float* outp = (float*)d_out;

    const int NB_SCAN = (NN + 255) / 256;  // 196
    const int EB = (EE + 255) / 256;
    const int NW4 = (NN + 3) / 4;  // wave-per-node kernels, 4 waves/block
    const int MB = (NN + 63) / 64; // 782

    hipMemsetAsync(deg, 0, (size_t)NN * 4, stream);
    hipMemsetAsync(bn_sums, 0, 3 * 256 * 4, stream);

    k_count_deg<<<EB, 256, 0, stream>>>(ei, deg);
    k_scan1<<<NB_SCAN, 256, 0, stream>>>(deg, row_start, blk);
    k_scan2<<<1, 256, 0, stream>>>(blk, NB_SCAN);
    k_scan3<<<NB_SCAN, 256, 0, stream>>>(row_start, blk, deg, cursor, dinv, inv_sage);
    k_fill<<<EB, 256, 0, stream>>>(ei, cursor, csr);

    // Layer 1: GCN
    k_gemm<false, false><<<dim3(MB, 2), 256, 0, stream>>>(x, W1, nullptr, bufB, NN, 128);
    k_gcn_agg<<<NW4, 256, 0, stream>>>(bufB, row_start, deg, csr, dinv, b1, bufA);
    k_bn_stats<<<400, 128, 0, stream>>>(bufA, bn_sums);
    k_bn_fin<<<1, 128, 0, stream>>>(bn_sums, gamma1, beta1, bn_coef);
    k_bn_elu<<<(NN * 32 + 255) / 256, 256, 0, stream>>>(bufA, bn_coef);

    // Layer 2: SAGE
    k_sage_agg<<<NW4, 256, 0, stream>>>(bufA, row_start, deg, csr, inv_sage, bufB);
    k_gemm<false, true><<<dim3(MB, 2), 256, 0, stream>>>(bufB, Wl, bl, bufC, NN, 128);
    k_gemm<true, false><<<dim3(MB, 2), 256, 0, stream>>>(bufA, Wr, nullptr, bufC, NN, 128);
    k_bn_stats<<<400, 128, 0, stream>>>(bufC, bn_sums + 256);
    k_bn_fin<<<1, 128, 0, stream>>>(bn_sums + 256, gamma2, beta2, bn_coef);
    k_bn_elu<<<(NN * 32 + 255) / 256, 256, 0, stream>>>(bufC, bn_coef);

    // Layer 3: GAT
    k_gemm<false, false><<<dim3(MB, 6), 256, 0, stream>>>(bufC, W3, nullptr, buf3, NN, 384);
    k_att<<<NW4, 256, 0, stream>>>(buf3, att_src, att_dst, asrc, adst);
    k_gat_agg<<<NW4, 256, 0, stream>>>(buf3, row_start, deg, csr, asrc, adst, b3, bufB);
    k_bn_stats<<<400, 128, 0, stream>>>(bufB, bn_sums + 512);
    k_bn_fin<<<1, 128, 0, stream>>>(bn_sums + 512, gamma3, beta3, bn_coef);
    k_bn_elu<<<(NN * 32 + 255) / 256, 256, 0, stream>>>(bufB, bn_coef);

    // Pool + classifier
    k_pool<<<GG, 128, 0, stream>>>(bufB, batch, outp);
    k_logits<<<(GG * CC + 255) / 256, 256, 0, stream>>>(outp, Wc, bc, outp + GG * HH);
}

// Round 2
// 814.827 us; speedup vs baseline: 1.2189x; 1.2189x over previous
//
#include <hip/hip_runtime.h>
#include <math.h>

#define NN 50000
#define EE 500000
#define HH 128
#define NHEADS 3
#define CC 10
#define GG 64
#define EPSV 1e-5f
#define SLOPE 0.2f

// ---------------- CSR build ----------------

__global__ void k_count_deg(const int* __restrict__ ei, int* __restrict__ deg) {
    int e = blockIdx.x * 256 + threadIdx.x;
    if (e < EE) atomicAdd(&deg[ei[EE + e]], 1);
}

__global__ void k_scan1(const int* __restrict__ deg, int* __restrict__ row_start,
                        int* __restrict__ blk) {
    __shared__ int s[256];
    int i = blockIdx.x * 256 + threadIdx.x;
    int v = (i < NN) ? deg[i] : 0;
    s[threadIdx.x] = v;
    __syncthreads();
    for (int o = 1; o < 256; o <<= 1) {
        int t = (threadIdx.x >= o) ? s[threadIdx.x - o] : 0;
        __syncthreads();
        s[threadIdx.x] += t;
        __syncthreads();
    }
    if (i < NN) row_start[i] = s[threadIdx.x] - v;  // exclusive
    if (threadIdx.x == 255) blk[blockIdx.x] = s[255];
}

__global__ void k_scan2(int* __restrict__ blk, int nb) {
    __shared__ int s[256];
    int v = (threadIdx.x < nb) ? blk[threadIdx.x] : 0;
    s[threadIdx.x] = v;
    __syncthreads();
    for (int o = 1; o < 256; o <<= 1) {
        int t = (threadIdx.x >= o) ? s[threadIdx.x - o] : 0;
        __syncthreads();
        s[threadIdx.x] += t;
        __syncthreads();
    }
    if (threadIdx.x < nb) blk[threadIdx.x] = s[threadIdx.x] - v;  // exclusive
}

__global__ void k_scan3(int* __restrict__ row_start, const int* __restrict__ blk,
                        const int* __restrict__ deg, int* __restrict__ cursor,
                        float* __restrict__ dinv, float* __restrict__ inv_sage) {
    int i = blockIdx.x * 256 + threadIdx.x;
    if (i < NN) {
        int rs = row_start[i] + blk[blockIdx.x];
        row_start[i] = rs;
        cursor[i] = rs;
        int d = deg[i];
        dinv[i] = rsqrtf((float)(d + 1));
        inv_sage[i] = 1.0f / (float)(d > 1 ? d : 1);
    }
}

__global__ void k_fill(const int* __restrict__ ei, int* __restrict__ cursor,
                       int* __restrict__ csr_src) {
    int e = blockIdx.x * 256 + threadIdx.x;
    if (e < EE) {
        int d = ei[EE + e];
        int p = atomicAdd(&cursor[d], 1);
        csr_src[p] = ei[e];
    }
}

// ---------------- GEMM (fp32, K=128, BM=BN=64, 256 threads) ----------------

template <bool ACC, bool BIAS>
__global__ __launch_bounds__(256) void k_gemm(const float* __restrict__ A,
                                              const float* __restrict__ B,
                                              const float* __restrict__ bias,
                                              float* __restrict__ C, int M, int Nn) {
    __shared__ float AsT[128 * 68];  // [k][r], stride 68
    __shared__ float Bs[128 * 64];   // [k][c]
    int tid = threadIdx.x;
    int rBase = blockIdx.x * 64, cBase = blockIdx.y * 64;

#pragma unroll
    for (int q = 0; q < 8; q++) {
        int slot = q * 256 + tid;
        int r = slot >> 5, k4 = slot & 31;
        float4 v = make_float4(0.f, 0.f, 0.f, 0.f);
        int gr = rBase + r;
        if (gr < M) v = *(const float4*)(A + (size_t)gr * 128 + k4 * 4);
        AsT[(k4 * 4 + 0) * 68 + r] = v.x;
        AsT[(k4 * 4 + 1) * 68 + r] = v.y;
        AsT[(k4 * 4 + 2) * 68 + r] = v.z;
        AsT[(k4 * 4 + 3) * 68 + r] = v.w;
    }
#pragma unroll
    for (int q = 0; q < 8; q++) {
        int slot = q * 256 + tid;
        int k = slot >> 4, c4 = slot & 15;
        *(float4*)(Bs + k * 64 + c4 * 4) = *(const float4*)(B + (size_t)k * Nn + cBase + c4 * 4);
    }
    __syncthreads();

    int tr = tid >> 4, tc = tid & 15;
    float acc[4][4];
#pragma unroll
    for (int i = 0; i < 4; i++)
#pragma unroll
        for (int j = 0; j < 4; j++) acc[i][j] = 0.f;

#pragma unroll 8
    for (int k = 0; k < 128; k++) {
        float4 a = *(const float4*)(AsT + k * 68 + tr * 4);
        float4 b = *(const float4*)(Bs + k * 64 + tc * 4);
        acc[0][0] += a.x * b.x; acc[0][1] += a.x * b.y; acc[0][2] += a.x * b.z; acc[0][3] += a.x * b.w;
        acc[1][0] += a.y * b.x; acc[1][1] += a.y * b.y; acc[1][2] += a.y * b.z; acc[1][3] += a.y * b.w;
        acc[2][0] += a.z * b.x; acc[2][1] += a.z * b.y; acc[2][2] += a.z * b.z; acc[2][3] += a.z * b.w;
        acc[3][0] += a.w * b.x; acc[3][1] += a.w * b.y; acc[3][2] += a.w * b.z; acc[3][3] += a.w * b.w;
    }

#pragma unroll
    for (int i = 0; i < 4; i++) {
        int r = rBase + tr * 4 + i;
        if (r < M) {
            float4 o = make_float4(acc[i][0], acc[i][1], acc[i][2], acc[i][3]);
            size_t cidx = (size_t)r * Nn + cBase + tc * 4;
            if (BIAS) {
                float4 bb = *(const float4*)(bias + cBase + tc * 4);
                o.x += bb.x; o.y += bb.y; o.z += bb.z; o.w += bb.w;
            }
            if (ACC) {
                float4 cc = *(const float4*)(C + cidx);
                o.x += cc.x; o.y += cc.y; o.z += cc.z; o.w += cc.w;
            }
            *(float4*)(C + cidx) = o;
        }
    }
}

// ---------------- Aggregations (1 wave per node) ----------------

__global__ void k_gcn_agg(const float* __restrict__ h, const int* __restrict__ row_start,
                          const int* __restrict__ deg, const int* __restrict__ csr,
                          const float* __restrict__ dinv, const float* __restrict__ b1,
                          float* __restrict__ out) {
    int n = blockIdx.x * 4 + (threadIdx.x >> 6);
    if (n >= NN) return;
    int lane = threadIdx.x & 63;
    const float2* hp = (const float2*)h;
    float di = dinv[n];
    float2 hv = hp[(size_t)n * 64 + lane];
    float ws = di * di;
    float2 acc;
    acc.x = hv.x * ws;
    acc.y = hv.y * ws;
    int s0 = row_start[n], cnt = deg[n];
    for (int i = 0; i < cnt; i++) {
        int s = csr[s0 + i];
        float w = dinv[s] * di;
        float2 v = hp[(size_t)s * 64 + lane];
        acc.x += v.x * w;
        acc.y += v.y * w;
    }
    float2 bb = ((const float2*)b1)[lane];
    acc.x += bb.x;
    acc.y += bb.y;
    ((float2*)out)[(size_t)n * 64 + lane] = acc;
}

__global__ void k_sage_agg(const float* __restrict__ h, const int* __restrict__ row_start,
                           const int* __restrict__ deg, const int* __restrict__ csr,
                           const float* __restrict__ inv_sage, float* __restrict__ out) {
    int n = blockIdx.x * 4 + (threadIdx.x >> 6);
    if (n >= NN) return;
    int lane = threadIdx.x & 63;
    const float2* hp = (const float2*)h;
    float2 acc = make_float2(0.f, 0.f);
    int s0 = row_start[n], cnt = deg[n];
    for (int i = 0; i < cnt; i++) {
        int s = csr[s0 + i];
        float2 v = hp[(size_t)s * 64 + lane];
        acc.x += v.x;
        acc.y += v.y;
    }
    float sc = inv_sage[n];
    acc.x *= sc;
    acc.y *= sc;
    ((float2*)out)[(size_t)n * 64 + lane] = acc;
}

__global__ void k_att(const float* __restrict__ h3, const float* __restrict__ att_src,
                      const float* __restrict__ att_dst, float* __restrict__ asrc,
                      float* __restrict__ adst) {
    int n = blockIdx.x * 4 + (threadIdx.x >> 6);
    if (n >= NN) return;
    int lane = threadIdx.x & 63;
    const float* row = h3 + (size_t)n * 384;
#pragma unroll
    for (int hd = 0; hd < 3; hd++) {
        float v0 = row[hd * 128 + lane];
        float v1 = row[hd * 128 + 64 + lane];
        float s1 = v0 * att_src[hd * 128 + lane] + v1 * att_src[hd * 128 + 64 + lane];
        float s2 = v0 * att_dst[hd * 128 + lane] + v1 * att_dst[hd * 128 + 64 + lane];
        for (int o = 32; o > 0; o >>= 1) {
            s1 += __shfl_down(s1, o, 64);
            s2 += __shfl_down(s2, o, 64);
        }
        if (lane == 0) {
            asrc[n * 3 + hd] = s1;
            adst[n * 3 + hd] = s2;
        }
    }
}

__device__ __forceinline__ float lrelu(float a) { return fmaxf(a, SLOPE * a); }

__global__ void k_gat_agg(const float* __restrict__ h3, const int* __restrict__ row_start,
                          const int* __restrict__ deg, const int* __restrict__ csr,
                          const float* __restrict__ asrc, const float* __restrict__ adst,
                          const float* __restrict__ b3, float* __restrict__ out) {
    int n = blockIdx.x * 4 + (threadIdx.x >> 6);
    if (n >= NN) return;
    int lane = threadIdx.x & 63;
    const float2* hp = (const float2*)h3;  // row stride = 192 float2
    float ad0 = adst[n * 3 + 0], ad1 = adst[n * 3 + 1], ad2 = adst[n * 3 + 2];
    // self loop
    float m0 = lrelu(asrc[n * 3 + 0] + ad0);
    float m1 = lrelu(asrc[n * 3 + 1] + ad1);
    float m2 = lrelu(asrc[n * 3 + 2] + ad2);
    float l0 = 1.f, l1 = 1.f, l2 = 1.f;
    size_t base = (size_t)n * 192;
    float2 a0 = hp[base + 0 + lane];
    float2 a1 = hp[base + 64 + lane];
    float2 a2 = hp[base + 128 + lane];
    int s0r = row_start[n], cnt = deg[n];
    for (int i = 0; i < cnt; i++) {
        int s = csr[s0r + i];
        float e0 = lrelu(asrc[s * 3 + 0] + ad0);
        float e1 = lrelu(asrc[s * 3 + 1] + ad1);
        float e2 = lrelu(asrc[s * 3 + 2] + ad2);
        size_t sb = (size_t)s * 192;
        float2 v0 = hp[sb + 0 + lane];
        float2 v1 = hp[sb + 64 + lane];
        float2 v2 = hp[sb + 128 + lane];
        float mn, sc, w;
        mn = fmaxf(m0, e0); sc = __expf(m0 - mn); w = __expf(e0 - mn);
        l0 = l0 * sc + w; a0.x = a0.x * sc + w * v0.x; a0.y = a0.y * sc + w * v0.y; m0 = mn;
        mn = fmaxf(m1, e1); sc = __expf(m1 - mn); w = __expf(e1 - mn);
        l1 = l1 * sc + w; a1.x = a1.x * sc + w * v1.x; a1.y = a1.y * sc + w * v1.y; m1 = mn;
        mn = fmaxf(m2, e2); sc = __expf(m2 - mn); w = __expf(e2 - mn);
        l2 = l2 * sc + w; a2.x = a2.x * sc + w * v2.x; a2.y = a2.y * sc + w * v2.y; m2 = mn;
    }
    float r0 = 1.f / l0, r1 = 1.f / l1, r2 = 1.f / l2;
    float2 bb = ((const float2*)b3)[lane];
    float2 o;
    o.x = (a0.x * r0 + a1.x * r1 + a2.x * r2) * (1.f / 3.f) + bb.x;
    o.y = (a0.y * r0 + a1.y * r1 + a2.y * r2) * (1.f / 3.f) + bb.y;
    ((float2*)out)[(size_t)n * 64 + lane] = o;
}

// ---------------- BatchNorm + ELU ----------------

__global__ void k_bn_stats(const float* __restrict__ h, float* __restrict__ sums) {
    int f = threadIdx.x;  // 128 threads
    int rows_per = (NN + gridDim.x - 1) / gridDim.x;
    int r0 = blockIdx.x * rows_per;
    int r1 = r0 + rows_per;
    if (r1 > NN) r1 = NN;
    float s = 0.f, sq = 0.f;
    for (int r = r0; r < r1; r++) {
        float v = h[(size_t)r * 128 + f];
        s += v;
        sq += v * v;
    }
    atomicAdd(&sums[f], s);
    atomicAdd(&sums[128 + f], sq);
}

__global__ void k_bn_fin(const float* __restrict__ sums, const float* __restrict__ gamma,
                         const float* __restrict__ beta, float* __restrict__ coef) {
    int f = threadIdx.x;
    float mu = sums[f] * (1.0f / NN);
    float var = sums[128 + f] * (1.0f / NN) - mu * mu;
    float rs = rsqrtf(var + EPSV);
    float sc = rs * gamma[f];
    coef[f] = sc;
    coef[128 + f] = beta[f] - mu * sc;
}

__device__ __forceinline__ float elu1(float x) { return x > 0.f ? x : (__expf(x) - 1.f); }

__global__ void k_bn_elu(float* __restrict__ h, const float* __restrict__ coef) {
    int i = blockIdx.x * 256 + threadIdx.x;
    if (i >= NN * 32) return;
    int f4 = (i & 31) << 2;
    float4 v = ((float4*)h)[i];
    float4 sc = *(const float4*)(coef + f4);
    float4 sh = *(const float4*)(coef + 128 + f4);
    v.x = elu1(v.x * sc.x + sh.x);
    v.y = elu1(v.y * sc.y + sh.y);
    v.z = elu1(v.z * sc.z + sh.z);
    v.w = elu1(v.w * sc.w + sh.w);
    ((float4*)h)[i] = v;
}

// ---------------- Pool (two-stage, parallel) + classifier ----------------

#define POOL_BLOCKS 800

__global__ void k_pool_partial(const float* __restrict__ h, const int* __restrict__ batch,
                               float* __restrict__ pool, float* __restrict__ cntf) {
    const int RP = (NN + POOL_BLOCKS - 1) / POOL_BLOCKS;  // 63
    int r0 = blockIdx.x * RP;
    int r1 = r0 + RP;
    if (r1 > NN) r1 = NN;
    if (r0 >= r1) return;
    int f = threadIdx.x;  // 128 threads (feature)
    int g = batch[r0];
    float s = 0.f, c = 0.f;
    for (int r = r0; r < r1; r++) {
        int gr = batch[r];
        if (gr != g) {
            atomicAdd(&pool[g * 128 + f], s);
            if (f == 0) atomicAdd(&cntf[g], c);
            s = 0.f; c = 0.f; g = gr;
        }
        s += h[(size_t)r * 128 + f];
        c += 1.f;
    }
    atomicAdd(&pool[g * 128 + f], s);
    if (f == 0) atomicAdd(&cntf[g], c);
}

__global__ void k_pool_fin(const float* __restrict__ pool, const float* __restrict__ cntf,
                           float* __restrict__ out) {
    int g = blockIdx.x;  // GG blocks x 128 threads
    int f = threadIdx.x;
    float c = cntf[g];
    out[g * 128 + f] = pool[g * 128 + f] / fmaxf(c, 1.f);
}

__global__ void k_logits(const float* __restrict__ pooled, const float* __restrict__ Wc,
                         const float* __restrict__ bc, float* __restrict__ out) {
    int i = blockIdx.x * 256 + threadIdx.x;
    if (i >= GG * CC) return;
    int g = i / CC, c = i % CC;
    float s = bc[c];
    for (int k = 0; k < 128; k++) s += pooled[g * 128 + k] * Wc[k * CC + c];
    out[i] = s;
}

// ---------------- launch ----------------

extern "C" void kernel_launch(void* const* d_in, const int* in_sizes, int n_in,
                              void* d_out, int out_size, void* d_ws, size_t ws_size,
                              hipStream_t stream) {
    const float* x = (const float*)d_in[0];
    const int* ei = (const int*)d_in[1];
    const int* batch = (const int*)d_in[2];
    const float* W1 = (const float*)d_in[3];
    const float* b1 = (const float*)d_in[4];
    const float* gamma1 = (const float*)d_in[5];
    const float* beta1 = (const float*)d_in[6];
    const float* Wl = (const float*)d_in[7];
    const float* bl = (const float*)d_in[8];
    const float* Wr = (const float*)d_in[9];
    const float* gamma2 = (const float*)d_in[10];
    const float* beta2 = (const float*)d_in[11];
    const float* W3 = (const float*)d_in[12];
    const float* att_src = (const float*)d_in[13];
    const float* att_dst = (const float*)d_in[14];
    const float* b3 = (const float*)d_in[15];
    const float* gamma3 = (const float*)d_in[16];
    const float* beta3 = (const float*)d_in[17];
    const float* Wc = (const float*)d_in[18];
    const float* bc = (const float*)d_in[19];

    char* w = (char*)d_ws;
    const size_t SZ_NH = (size_t)NN * 128 * 4;  // 25.6 MB
    float* bufA = (float*)(w + 0);
    float* bufB = (float*)(w + SZ_NH);
    float* bufC = (float*)(w + 2 * SZ_NH);
    float* buf3 = (float*)(w + 3 * SZ_NH);            // N x 384
    size_t o = 3 * SZ_NH + (size_t)NN * 384 * 4;      // 153.6 MB
    int* csr = (int*)(w + o); o += (size_t)EE * 4;
    int* deg = (int*)(w + o); o += (size_t)NN * 4;
    int* row_start = (int*)(w + o); o += (size_t)NN * 4;
    int* cursor = (int*)(w + o); o += (size_t)NN * 4;
    float* dinv = (float*)(w + o); o += (size_t)NN * 4;
    float* inv_sage = (float*)(w + o); o += (size_t)NN * 4;
    float* asrc = (float*)(w + o); o += (size_t)NN * 3 * 4;
    float* adst = (float*)(w + o); o += (size_t)NN * 3 * 4;
    float* bn_sums = (float*)(w + o); o += 3 * 256 * 4;
    float* bn_coef = (float*)(w + o); o += 256 * 4;
    int* blk = (int*)(w + o); o += 1024;
    float* poolacc = (float*)(w + o); o += (size_t)GG * 128 * 4;
    float* cntf = (float*)(w + o); o += (size_t)GG * 4;

    float* outp = (float*)d_out;

    const int NB_SCAN = (NN + 255) / 256;  // 196
    const int EB = (EE + 255) / 256;
    const int NW4 = (NN + 3) / 4;  // wave-per-node kernels, 4 waves/block
    const int MB = (NN + 63) / 64; // 782

    hipMemsetAsync(deg, 0, (size_t)NN * 4, stream);
    hipMemsetAsync(bn_sums, 0, 3 * 256 * 4, stream);
    hipMemsetAsync(poolacc, 0, ((size_t)GG * 128 + GG) * 4, stream);  // poolacc + cntf contiguous

    k_count_deg<<<EB, 256, 0, stream>>>(ei, deg);
    k_scan1<<<NB_SCAN, 256, 0, stream>>>(deg, row_start, blk);
    k_scan2<<<1, 256, 0, stream>>>(blk, NB_SCAN);
    k_scan3<<<NB_SCAN, 256, 0, stream>>>(row_start, blk, deg, cursor, dinv, inv_sage);
    k_fill<<<EB, 256, 0, stream>>>(ei, cursor, csr);

    // Layer 1: GCN
    k_gemm<false, false><<<dim3(MB, 2), 256, 0, stream>>>(x, W1, nullptr, bufB, NN, 128);
    k_gcn_agg<<<NW4, 256, 0, stream>>>(bufB, row_start, deg, csr, dinv, b1, bufA);
    k_bn_stats<<<1024, 128, 0, stream>>>(bufA, bn_sums);
    k_bn_fin<<<1, 128, 0, stream>>>(bn_sums, gamma1, beta1, bn_coef);
    k_bn_elu<<<(NN * 32 + 255) / 256, 256, 0, stream>>>(bufA, bn_coef);

    // Layer 2: SAGE
    k_sage_agg<<<NW4, 256, 0, stream>>>(bufA, row_start, deg, csr, inv_sage, bufB);
    k_gemm<false, true><<<dim3(MB, 2), 256, 0, stream>>>(bufB, Wl, bl, bufC, NN, 128);
    k_gemm<true, false><<<dim3(MB, 2), 256, 0, stream>>>(bufA, Wr, nullptr, bufC, NN, 128);
    k_bn_stats<<<1024, 128, 0, stream>>>(bufC, bn_sums + 256);
    k_bn_fin<<<1, 128, 0, stream>>>(bn_sums + 256, gamma2, beta2, bn_coef);
    k_bn_elu<<<(NN * 32 + 255) / 256, 256, 0, stream>>>(bufC, bn_coef);

    // Layer 3: GAT
    k_gemm<false, false><<<dim3(MB, 6), 256, 0, stream>>>(bufC, W3, nullptr, buf3, NN, 384);
    k_att<<<NW4, 256, 0, stream>>>(buf3, att_src, att_dst, asrc, adst);
    k_gat_agg<<<NW4, 256, 0, stream>>>(buf3, row_start, deg, csr, asrc, adst, b3, bufB);
    k_bn_stats<<<1024, 128, 0, stream>>>(bufB, bn_sums + 512);
    k_bn_fin<<<1, 128, 0, stream>>>(bn_sums + 512, gamma3, beta3, bn_coef);
    k_bn_elu<<<(NN * 32 + 255) / 256, 256, 0, stream>>>(bufB, bn_coef);

    // Pool + classifier
    k_pool_partial<<<POOL_BLOCKS, 128, 0, stream>>>(bufB, batch, poolacc, cntf);
    k_pool_fin<<<GG, 128, 0, stream>>>(poolacc, cntf, outp);
    k_logits<<<(GG * CC + 255) / 256, 256, 0, stream>>>(outp, Wc, bc, outp + GG * HH);
}

// Round 3
// 791.560 us; speedup vs baseline: 1.2547x; 1.0294x over previous
//
#include <hip/hip_runtime.h>
#include <math.h>

#define NN 50000
#define EE 500000
#define HH 128
#define NHEADS 3
#define CC 10
#define GG 64
#define EPSV 1e-5f
#define SLOPE 0.2f

// ---------------- CSR build ----------------

__global__ void k_count_deg(const int* __restrict__ ei, int* __restrict__ deg) {
    int e = blockIdx.x * 256 + threadIdx.x;
    if (e < EE) atomicAdd(&deg[ei[EE + e]], 1);
}

__global__ void k_scan1(const int* __restrict__ deg, int* __restrict__ row_start,
                        int* __restrict__ blk) {
    __shared__ int s[256];
    int i = blockIdx.x * 256 + threadIdx.x;
    int v = (i < NN) ? deg[i] : 0;
    s[threadIdx.x] = v;
    __syncthreads();
    for (int o = 1; o < 256; o <<= 1) {
        int t = (threadIdx.x >= o) ? s[threadIdx.x - o] : 0;
        __syncthreads();
        s[threadIdx.x] += t;
        __syncthreads();
    }
    if (i < NN) row_start[i] = s[threadIdx.x] - v;  // exclusive
    if (threadIdx.x == 255) blk[blockIdx.x] = s[255];
}

__global__ void k_scan2(int* __restrict__ blk, int nb) {
    __shared__ int s[256];
    int v = (threadIdx.x < nb) ? blk[threadIdx.x] : 0;
    s[threadIdx.x] = v;
    __syncthreads();
    for (int o = 1; o < 256; o <<= 1) {
        int t = (threadIdx.x >= o) ? s[threadIdx.x - o] : 0;
        __syncthreads();
        s[threadIdx.x] += t;
        __syncthreads();
    }
    if (threadIdx.x < nb) blk[threadIdx.x] = s[threadIdx.x] - v;  // exclusive
}

__global__ void k_scan3(int* __restrict__ row_start, const int* __restrict__ blk,
                        const int* __restrict__ deg, int* __restrict__ cursor,
                        float* __restrict__ dinv, float* __restrict__ inv_sage) {
    int i = blockIdx.x * 256 + threadIdx.x;
    if (i < NN) {
        int rs = row_start[i] + blk[blockIdx.x];
        row_start[i] = rs;
        cursor[i] = rs;
        int d = deg[i];
        dinv[i] = rsqrtf((float)(d + 1));
        inv_sage[i] = 1.0f / (float)(d > 1 ? d : 1);
    }
}

__global__ void k_fill(const int* __restrict__ ei, int* __restrict__ cursor,
                       int* __restrict__ csr_src) {
    int e = blockIdx.x * 256 + threadIdx.x;
    if (e < EE) {
        int d = ei[EE + e];
        int p = atomicAdd(&cursor[d], 1);
        csr_src[p] = ei[e];
    }
}

// ---------------- GEMM (fp32, K = K128*128, BM=BN=64, 256 threads) ----------------

template <bool ACC, bool BIAS>
__global__ __launch_bounds__(256) void k_gemm(const float* __restrict__ A,
                                              const float* __restrict__ B,
                                              const float* __restrict__ bias,
                                              float* __restrict__ C, int M, int Nn,
                                              int K128, int strideA) {
    __shared__ float AsT[128 * 68];  // [k][r], stride 68
    __shared__ float Bs[128 * 64];   // [k][c]
    int tid = threadIdx.x;
    int rBase = blockIdx.x * 64, cBase = blockIdx.y * 64;
    int tr = tid >> 4, tc = tid & 15;

    float acc[4][4];
#pragma unroll
    for (int i = 0; i < 4; i++)
#pragma unroll
        for (int j = 0; j < 4; j++) acc[i][j] = 0.f;

    for (int kk = 0; kk < K128; kk++) {
#pragma unroll
        for (int q = 0; q < 8; q++) {
            int slot = q * 256 + tid;
            int r = slot >> 5, k4 = slot & 31;
            float4 v = make_float4(0.f, 0.f, 0.f, 0.f);
            int gr = rBase + r;
            if (gr < M) v = *(const float4*)(A + (size_t)gr * strideA + kk * 128 + k4 * 4);
            AsT[(k4 * 4 + 0) * 68 + r] = v.x;
            AsT[(k4 * 4 + 1) * 68 + r] = v.y;
            AsT[(k4 * 4 + 2) * 68 + r] = v.z;
            AsT[(k4 * 4 + 3) * 68 + r] = v.w;
        }
#pragma unroll
        for (int q = 0; q < 8; q++) {
            int slot = q * 256 + tid;
            int k = slot >> 4, c4 = slot & 15;
            *(float4*)(Bs + k * 64 + c4 * 4) =
                *(const float4*)(B + (size_t)(kk * 128 + k) * Nn + cBase + c4 * 4);
        }
        __syncthreads();

#pragma unroll 8
        for (int k = 0; k < 128; k++) {
            float4 a = *(const float4*)(AsT + k * 68 + tr * 4);
            float4 b = *(const float4*)(Bs + k * 64 + tc * 4);
            acc[0][0] += a.x * b.x; acc[0][1] += a.x * b.y; acc[0][2] += a.x * b.z; acc[0][3] += a.x * b.w;
            acc[1][0] += a.y * b.x; acc[1][1] += a.y * b.y; acc[1][2] += a.y * b.z; acc[1][3] += a.y * b.w;
            acc[2][0] += a.z * b.x; acc[2][1] += a.z * b.y; acc[2][2] += a.z * b.z; acc[2][3] += a.z * b.w;
            acc[3][0] += a.w * b.x; acc[3][1] += a.w * b.y; acc[3][2] += a.w * b.z; acc[3][3] += a.w * b.w;
        }
        __syncthreads();
    }

#pragma unroll
    for (int i = 0; i < 4; i++) {
        int r = rBase + tr * 4 + i;
        if (r < M) {
            float4 o = make_float4(acc[i][0], acc[i][1], acc[i][2], acc[i][3]);
            size_t cidx = (size_t)r * Nn + cBase + tc * 4;
            if (BIAS) {
                float4 bb = *(const float4*)(bias + cBase + tc * 4);
                o.x += bb.x; o.y += bb.y; o.z += bb.z; o.w += bb.w;
            }
            if (ACC) {
                float4 cc = *(const float4*)(C + cidx);
                o.x += cc.x; o.y += cc.y; o.z += cc.z; o.w += cc.w;
            }
            *(float4*)(C + cidx) = o;
        }
    }
}

// ---------------- Aggregations (1 wave per node) ----------------

__global__ void k_gcn_agg(const float* __restrict__ h, const int* __restrict__ row_start,
                          const int* __restrict__ deg, const int* __restrict__ csr,
                          const float* __restrict__ dinv, const float* __restrict__ b1,
                          float* __restrict__ out) {
    int n = blockIdx.x * 4 + (threadIdx.x >> 6);
    if (n >= NN) return;
    int lane = threadIdx.x & 63;
    const float2* hp = (const float2*)h;
    float di = dinv[n];
    float2 hv = hp[(size_t)n * 64 + lane];
    float ws = di * di;
    float2 acc;
    acc.x = hv.x * ws;
    acc.y = hv.y * ws;
    int s0 = row_start[n], cnt = deg[n];
    for (int i = 0; i < cnt; i++) {
        int s = csr[s0 + i];
        float w = dinv[s] * di;
        float2 v = hp[(size_t)s * 64 + lane];
        acc.x += v.x * w;
        acc.y += v.y * w;
    }
    float2 bb = ((const float2*)b1)[lane];
    acc.x += bb.x;
    acc.y += bb.y;
    ((float2*)out)[(size_t)n * 64 + lane] = acc;
}

__global__ void k_sage_agg(const float* __restrict__ h, const int* __restrict__ row_start,
                           const int* __restrict__ deg, const int* __restrict__ csr,
                           const float* __restrict__ inv_sage, float* __restrict__ out) {
    int n = blockIdx.x * 4 + (threadIdx.x >> 6);
    if (n >= NN) return;
    int lane = threadIdx.x & 63;
    const float2* hp = (const float2*)h;
    float2 acc = make_float2(0.f, 0.f);
    int s0 = row_start[n], cnt = deg[n];
    for (int i = 0; i < cnt; i++) {
        int s = csr[s0 + i];
        float2 v = hp[(size_t)s * 64 + lane];
        acc.x += v.x;
        acc.y += v.y;
    }
    float sc = inv_sage[n];
    acc.x *= sc;
    acc.y *= sc;
    ((float2*)out)[(size_t)n * 64 + lane] = acc;
}

// ---- GAT: fold attention vectors through W3 (tiny precompute) ----
// wsrc[h*128+k] = sum_j W3[k*384 + h*128 + j] * att_src[h*128+j]

__global__ void k_att_fold(const float* __restrict__ W3, const float* __restrict__ att_src,
                           const float* __restrict__ att_dst, float* __restrict__ wsrc,
                           float* __restrict__ wdst) {
    int tid = threadIdx.x;  // 384 threads: h = tid>>7, k = tid&127
    int h = tid >> 7, k = tid & 127;
    float s1 = 0.f, s2 = 0.f;
    const float* wrow = W3 + (size_t)k * 384 + h * 128;
    const float* as = att_src + h * 128;
    const float* ad = att_dst + h * 128;
    for (int j = 0; j < 128; j++) {
        float wv = wrow[j];
        s1 += wv * as[j];
        s2 += wv * ad[j];
    }
    wsrc[tid] = s1;
    wdst[tid] = s2;
}

// W3p[(h*128+k)*128 + c] = W3[k*384 + h*128 + c] / 3
__global__ void k_w3t(const float* __restrict__ W3, float* __restrict__ W3p) {
    int i = blockIdx.x * 256 + threadIdx.x;
    if (i >= 384 * 128) return;
    int h = i >> 14, k = (i >> 7) & 127, c = i & 127;
    W3p[i] = W3[(size_t)k * 384 + h * 128 + c] * (1.f / 3.f);
}

// attention logits directly from h2: asrc[n,h] = h2[n] . wsrc[h]
__global__ void k_att(const float* __restrict__ h2, const float* __restrict__ wsrc,
                      const float* __restrict__ wdst, float* __restrict__ asrc,
                      float* __restrict__ adst) {
    int n = blockIdx.x * 4 + (threadIdx.x >> 6);
    if (n >= NN) return;
    int lane = threadIdx.x & 63;
    const float2* hp = (const float2*)h2;
    const float2* ws2 = (const float2*)wsrc;
    const float2* wd2 = (const float2*)wdst;
    float2 hv = hp[(size_t)n * 64 + lane];
#pragma unroll
    for (int hd = 0; hd < 3; hd++) {
        float2 a = ws2[hd * 64 + lane];
        float2 b = wd2[hd * 64 + lane];
        float s1 = hv.x * a.x + hv.y * a.y;
        float s2 = hv.x * b.x + hv.y * b.y;
        for (int o = 32; o > 0; o >>= 1) {
            s1 += __shfl_down(s1, o, 64);
            s2 += __shfl_down(s2, o, 64);
        }
        if (lane == 0) {
            asrc[n * 3 + hd] = s1;
            adst[n * 3 + hd] = s2;
        }
    }
}

__device__ __forceinline__ float lrelu(float a) { return fmaxf(a, SLOPE * a); }

// aggregate h2 (one 512B gather/edge shared by all heads) with per-head online softmax.
// output layout: agg[n*384 + h*128 + f] (already alpha-normalized)
__global__ void k_gat_agg(const float* __restrict__ h2, const int* __restrict__ row_start,
                          const int* __restrict__ deg, const int* __restrict__ csr,
                          const float* __restrict__ asrc, const float* __restrict__ adst,
                          float* __restrict__ agg) {
    int n = blockIdx.x * 4 + (threadIdx.x >> 6);
    if (n >= NN) return;
    int lane = threadIdx.x & 63;
    const float2* hp = (const float2*)h2;
    float ad0 = adst[n * 3 + 0], ad1 = adst[n * 3 + 1], ad2 = adst[n * 3 + 2];
    // self loop (weight exp(0)=1 vs running max = own logit)
    float m0 = lrelu(asrc[n * 3 + 0] + ad0);
    float m1 = lrelu(asrc[n * 3 + 1] + ad1);
    float m2 = lrelu(asrc[n * 3 + 2] + ad2);
    float l0 = 1.f, l1 = 1.f, l2 = 1.f;
    float2 hv = hp[(size_t)n * 64 + lane];
    float2 a0 = hv, a1 = hv, a2 = hv;
    int s0r = row_start[n], cnt = deg[n];
    for (int i = 0; i < cnt; i++) {
        int s = csr[s0r + i];
        float e0 = lrelu(asrc[s * 3 + 0] + ad0);
        float e1 = lrelu(asrc[s * 3 + 1] + ad1);
        float e2 = lrelu(asrc[s * 3 + 2] + ad2);
        float2 v = hp[(size_t)s * 64 + lane];  // single gather, shared by 3 heads
        float mn, sc, w;
        mn = fmaxf(m0, e0); sc = __expf(m0 - mn); w = __expf(e0 - mn);
        l0 = l0 * sc + w; a0.x = a0.x * sc + w * v.x; a0.y = a0.y * sc + w * v.y; m0 = mn;
        mn = fmaxf(m1, e1); sc = __expf(m1 - mn); w = __expf(e1 - mn);
        l1 = l1 * sc + w; a1.x = a1.x * sc + w * v.x; a1.y = a1.y * sc + w * v.y; m1 = mn;
        mn = fmaxf(m2, e2); sc = __expf(m2 - mn); w = __expf(e2 - mn);
        l2 = l2 * sc + w; a2.x = a2.x * sc + w * v.x; a2.y = a2.y * sc + w * v.y; m2 = mn;
    }
    float r0 = 1.f / l0, r1 = 1.f / l1, r2 = 1.f / l2;
    float2* op = (float2*)agg + (size_t)n * 192;
    op[lane] = make_float2(a0.x * r0, a0.y * r0);
    op[64 + lane] = make_float2(a1.x * r1, a1.y * r1);
    op[128 + lane] = make_float2(a2.x * r2, a2.y * r2);
}

// ---------------- BatchNorm + ELU ----------------

__global__ void k_bn_stats(const float* __restrict__ h, float* __restrict__ sums) {
    int f = threadIdx.x;  // 128 threads
    int rows_per = (NN + gridDim.x - 1) / gridDim.x;
    int r0 = blockIdx.x * rows_per;
    int r1 = r0 + rows_per;
    if (r1 > NN) r1 = NN;
    float s = 0.f, sq = 0.f;
    for (int r = r0; r < r1; r++) {
        float v = h[(size_t)r * 128 + f];
        s += v;
        sq += v * v;
    }
    atomicAdd(&sums[f], s);
    atomicAdd(&sums[128 + f], sq);
}

__global__ void k_bn_fin(const float* __restrict__ sums, const float* __restrict__ gamma,
                         const float* __restrict__ beta, float* __restrict__ coef) {
    int f = threadIdx.x;
    float mu = sums[f] * (1.0f / NN);
    float var = sums[128 + f] * (1.0f / NN) - mu * mu;
    float rs = rsqrtf(var + EPSV);
    float sc = rs * gamma[f];
    coef[f] = sc;
    coef[128 + f] = beta[f] - mu * sc;
}

__device__ __forceinline__ float elu1(float x) { return x > 0.f ? x : (__expf(x) - 1.f); }

__global__ void k_bn_elu(float* __restrict__ h, const float* __restrict__ coef) {
    int i = blockIdx.x * 256 + threadIdx.x;
    if (i >= NN * 32) return;
    int f4 = (i & 31) << 2;
    float4 v = ((float4*)h)[i];
    float4 sc = *(const float4*)(coef + f4);
    float4 sh = *(const float4*)(coef + 128 + f4);
    v.x = elu1(v.x * sc.x + sh.x);
    v.y = elu1(v.y * sc.y + sh.y);
    v.z = elu1(v.z * sc.z + sh.z);
    v.w = elu1(v.w * sc.w + sh.w);
    ((float4*)h)[i] = v;
}

// ---------------- Pool (two-stage, parallel) + classifier ----------------

#define POOL_BLOCKS 800

__global__ void k_pool_partial(const float* __restrict__ h, const int* __restrict__ batch,
                               float* __restrict__ pool, float* __restrict__ cntf) {
    const int RP = (NN + POOL_BLOCKS - 1) / POOL_BLOCKS;  // 63
    int r0 = blockIdx.x * RP;
    int r1 = r0 + RP;
    if (r1 > NN) r1 = NN;
    if (r0 >= r1) return;
    int f = threadIdx.x;  // 128 threads (feature)
    int g = batch[r0];
    float s = 0.f, c = 0.f;
    for (int r = r0; r < r1; r++) {
        int gr = batch[r];
        if (gr != g) {
            atomicAdd(&pool[g * 128 + f], s);
            if (f == 0) atomicAdd(&cntf[g], c);
            s = 0.f; c = 0.f; g = gr;
        }
        s += h[(size_t)r * 128 + f];
        c += 1.f;
    }
    atomicAdd(&pool[g * 128 + f], s);
    if (f == 0) atomicAdd(&cntf[g], c);
}

__global__ void k_pool_fin(const float* __restrict__ pool, const float* __restrict__ cntf,
                           float* __restrict__ out) {
    int g = blockIdx.x;  // GG blocks x 128 threads
    int f = threadIdx.x;
    float c = cntf[g];
    out[g * 128 + f] = pool[g * 128 + f] / fmaxf(c, 1.f);
}

__global__ void k_logits(const float* __restrict__ pooled, const float* __restrict__ Wc,
                         const float* __restrict__ bc, float* __restrict__ out) {
    int i = blockIdx.x * 256 + threadIdx.x;
    if (i >= GG * CC) return;
    int g = i / CC, c = i % CC;
    float s = bc[c];
    for (int k = 0; k < 128; k++) s += pooled[g * 128 + k] * Wc[k * CC + c];
    out[i] = s;
}

// ---------------- launch ----------------

extern "C" void kernel_launch(void* const* d_in, const int* in_sizes, int n_in,
                              void* d_out, int out_size, void* d_ws, size_t ws_size,
                              hipStream_t stream) {
    const float* x = (const float*)d_in[0];
    const int* ei = (const int*)d_in[1];
    const int* batch = (const int*)d_in[2];
    const float* W1 = (const float*)d_in[3];
    const float* b1 = (const float*)d_in[4];
    const float* gamma1 = (const float*)d_in[5];
    const float* beta1 = (const float*)d_in[6];
    const float* Wl = (const float*)d_in[7];
    const float* bl = (const float*)d_in[8];
    const float* Wr = (const float*)d_in[9];
    const float* gamma2 = (const float*)d_in[10];
    const float* beta2 = (const float*)d_in[11];
    const float* W3 = (const float*)d_in[12];
    const float* att_src = (const float*)d_in[13];
    const float* att_dst = (const float*)d_in[14];
    const float* b3 = (const float*)d_in[15];
    const float* gamma3 = (const float*)d_in[16];
    const float* beta3 = (const float*)d_in[17];
    const float* Wc = (const float*)d_in[18];
    const float* bc = (const float*)d_in[19];

    char* w = (char*)d_ws;
    const size_t SZ_NH = (size_t)NN * 128 * 4;  // 25.6 MB
    float* bufA = (float*)(w + 0);
    float* bufB = (float*)(w + SZ_NH);
    float* bufC = (float*)(w + 2 * SZ_NH);
    float* aggD = (float*)(w + 3 * SZ_NH);            // N x 384
    size_t o = 3 * SZ_NH + (size_t)NN * 384 * 4;      // 153.6 MB
    int* csr = (int*)(w + o); o += (size_t)EE * 4;
    int* deg = (int*)(w + o); o += (size_t)NN * 4;
    int* row_start = (int*)(w + o); o += (size_t)NN * 4;
    int* cursor = (int*)(w + o); o += (size_t)NN * 4;
    float* dinv = (float*)(w + o); o += (size_t)NN * 4;
    float* inv_sage = (float*)(w + o); o += (size_t)NN * 4;
    float* asrc = (float*)(w + o); o += (size_t)NN * 3 * 4;
    float* adst = (float*)(w + o); o += (size_t)NN * 3 * 4;
    float* bn_sums = (float*)(w + o); o += 3 * 256 * 4;
    float* bn_coef = (float*)(w + o); o += 256 * 4;
    int* blk = (int*)(w + o); o += 1024;
    float* poolacc = (float*)(w + o); o += (size_t)GG * 128 * 4;
    float* cntf = (float*)(w + o); o += (size_t)GG * 4;
    float* wsrc = (float*)(w + o); o += 384 * 4;
    float* wdst = (float*)(w + o); o += 384 * 4;
    float* W3p = (float*)(w + o); o += (size_t)384 * 128 * 4;

    float* outp = (float*)d_out;

    const int NB_SCAN = (NN + 255) / 256;  // 196
    const int EB = (EE + 255) / 256;
    const int NW4 = (NN + 3) / 4;  // wave-per-node kernels, 4 waves/block
    const int MB = (NN + 63) / 64; // 782

    hipMemsetAsync(deg, 0, (size_t)NN * 4, stream);
    hipMemsetAsync(bn_sums, 0, 3 * 256 * 4, stream);
    hipMemsetAsync(poolacc, 0, ((size_t)GG * 128 + GG) * 4, stream);  // poolacc + cntf contiguous

    k_count_deg<<<EB, 256, 0, stream>>>(ei, deg);
    k_scan1<<<NB_SCAN, 256, 0, stream>>>(deg, row_start, blk);
    k_scan2<<<1, 256, 0, stream>>>(blk, NB_SCAN);
    k_scan3<<<NB_SCAN, 256, 0, stream>>>(row_start, blk, deg, cursor, dinv, inv_sage);
    k_fill<<<EB, 256, 0, stream>>>(ei, cursor, csr);
    // tiny precomputes for GAT (independent of node data — run early, overlap)
    k_att_fold<<<1, 384, 0, stream>>>(W3, att_src, att_dst, wsrc, wdst);
    k_w3t<<<(384 * 128 + 255) / 256, 256, 0, stream>>>(W3, W3p);

    // Layer 1: GCN
    k_gemm<false, false><<<dim3(MB, 2), 256, 0, stream>>>(x, W1, nullptr, bufB, NN, 128, 1, 128);
    k_gcn_agg<<<NW4, 256, 0, stream>>>(bufB, row_start, deg, csr, dinv, b1, bufA);
    k_bn_stats<<<1024, 128, 0, stream>>>(bufA, bn_sums);
    k_bn_fin<<<1, 128, 0, stream>>>(bn_sums, gamma1, beta1, bn_coef);
    k_bn_elu<<<(NN * 32 + 255) / 256, 256, 0, stream>>>(bufA, bn_coef);

    // Layer 2: SAGE
    k_sage_agg<<<NW4, 256, 0, stream>>>(bufA, row_start, deg, csr, inv_sage, bufB);
    k_gemm<false, true><<<dim3(MB, 2), 256, 0, stream>>>(bufB, Wl, bl, bufC, NN, 128, 1, 128);
    k_gemm<true, false><<<dim3(MB, 2), 256, 0, stream>>>(bufA, Wr, nullptr, bufC, NN, 128, 1, 128);
    k_bn_stats<<<1024, 128, 0, stream>>>(bufC, bn_sums + 256);
    k_bn_fin<<<1, 128, 0, stream>>>(bn_sums + 256, gamma2, beta2, bn_coef);
    k_bn_elu<<<(NN * 32 + 255) / 256, 256, 0, stream>>>(bufC, bn_coef);

    // Layer 3: GAT (aggregate-then-transform)
    k_att<<<NW4, 256, 0, stream>>>(bufC, wsrc, wdst, asrc, adst);
    k_gat_agg<<<NW4, 256, 0, stream>>>(bufC, row_start, deg, csr, asrc, adst, aggD);
    k_gemm<false, true><<<dim3(MB, 2), 256, 0, stream>>>(aggD, W3p, b3, bufA, NN, 128, 3, 384);
    k_bn_stats<<<1024, 128, 0, stream>>>(bufA, bn_sums + 512);
    k_bn_fin<<<1, 128, 0, stream>>>(bn_sums + 512, gamma3, beta3, bn_coef);
    k_bn_elu<<<(NN * 32 + 255) / 256, 256, 0, stream>>>(bufA, bn_coef);

    // Pool + classifier
    k_pool_partial<<<POOL_BLOCKS, 128, 0, stream>>>(bufA, batch, poolacc, cntf);
    k_pool_fin<<<GG, 128, 0, stream>>>(poolacc, cntf, outp);
    k_logits<<<(GG * CC + 255) / 256, 256, 0, stream>>>(outp, Wc, bc, outp + GG * HH);
}

// Round 4
// 676.424 us; speedup vs baseline: 1.4682x; 1.1702x over previous
//
#include <hip/hip_runtime.h>
#include <math.h>

#define NN 50000
#define EE 500000
#define HH 128
#define NHEADS 3
#define CC 10
#define GG 64
#define EPSV 1e-5f
#define SLOPE 0.2f

typedef __attribute__((ext_vector_type(8))) short short8;
typedef __attribute__((ext_vector_type(4))) float f32x4;

// ---------------- CSR build ----------------

__global__ void k_count_deg(const int* __restrict__ ei, int* __restrict__ deg) {
    int e = blockIdx.x * 256 + threadIdx.x;
    if (e < EE) atomicAdd(&deg[ei[EE + e]], 1);
}

__global__ void k_scan1(const int* __restrict__ deg, int* __restrict__ row_start,
                        int* __restrict__ blk) {
    __shared__ int s[256];
    int i = blockIdx.x * 256 + threadIdx.x;
    int v = (i < NN) ? deg[i] : 0;
    s[threadIdx.x] = v;
    __syncthreads();
    for (int o = 1; o < 256; o <<= 1) {
        int t = (threadIdx.x >= o) ? s[threadIdx.x - o] : 0;
        __syncthreads();
        s[threadIdx.x] += t;
        __syncthreads();
    }
    if (i < NN) row_start[i] = s[threadIdx.x] - v;  // exclusive
    if (threadIdx.x == 255) blk[blockIdx.x] = s[255];
}

__global__ void k_scan2(int* __restrict__ blk, int nb) {
    __shared__ int s[256];
    int v = (threadIdx.x < nb) ? blk[threadIdx.x] : 0;
    s[threadIdx.x] = v;
    __syncthreads();
    for (int o = 1; o < 256; o <<= 1) {
        int t = (threadIdx.x >= o) ? s[threadIdx.x - o] : 0;
        __syncthreads();
        s[threadIdx.x] += t;
        __syncthreads();
    }
    if (threadIdx.x < nb) blk[threadIdx.x] = s[threadIdx.x] - v;  // exclusive
}

__global__ void k_scan3(int* __restrict__ row_start, const int* __restrict__ blk,
                        const int* __restrict__ deg, int* __restrict__ cursor,
                        float* __restrict__ dinv, float* __restrict__ inv_sage) {
    int i = blockIdx.x * 256 + threadIdx.x;
    if (i < NN) {
        int rs = row_start[i] + blk[blockIdx.x];
        row_start[i] = rs;
        cursor[i] = rs;
        int d = deg[i];
        dinv[i] = rsqrtf((float)(d + 1));
        inv_sage[i] = 1.0f / (float)(d > 1 ? d : 1);
    }
}

__global__ void k_fill(const int* __restrict__ ei, int* __restrict__ cursor,
                       int* __restrict__ csr_src) {
    int e = blockIdx.x * 256 + threadIdx.x;
    if (e < EE) {
        int d = ei[EE + e];
        int p = atomicAdd(&cursor[d], 1);
        csr_src[p] = ei[e];
    }
}

// ---------------- Weight prep: fp32 -> fragment-ordered bf16 hi/lo ----------------
// Fragment order for mfma_f32_16x16x32_bf16, K chunked by 64, N groups of 16:
// element (k,n): c=k>>6, s=(k>>5)&1, quad=(k>>3)&3, j=k&7, G=n>>4, l=quad*16+(n&15)
// dst = ((((c*2+s)*8 + G)*64) + l)*8 + j

__global__ void k_prep_w(const float* __restrict__ W, short* __restrict__ hi,
                         short* __restrict__ lo, int kelems, int cBase) {
    int i = blockIdx.x * 256 + threadIdx.x;
    if (i >= kelems) return;
    int k = i >> 7, n = i & 127;
    int c = (k >> 6) + cBase;
    int s = (k >> 5) & 1, quad = (k >> 3) & 3, j = k & 7;
    int G = n >> 4, l = quad * 16 + (n & 15);
    size_t dst = ((((size_t)(c * 2 + s)) * 8 + G) * 64 + l) * 8 + j;
    float x = W[i];
    unsigned int ux = __builtin_bit_cast(unsigned int, x);
    unsigned short hx = (unsigned short)(ux >> 16);
    float fx = __builtin_bit_cast(float, ux & 0xffff0000u);
    unsigned short lx = (unsigned short)(__builtin_bit_cast(unsigned int, x - fx) >> 16);
    hi[dst] = (short)hx;
    lo[dst] = (short)lx;
}

// ---------------- MFMA GEMM (split-bf16, C = [A1|A2] @ B + bias) ----------------
// Block tile 128x128, 4 waves, wave tile 64x64 (4x4 MFMA tiles of 16x16).
// K chunked by 64 (2 MFMA k-steps of 32). A staged in LDS (hi/lo shorts, stride 72).
// B read directly from global in fragment order (L2-resident weights).

__global__ __launch_bounds__(256) void k_gemm_mfma(
    const float* __restrict__ A1, const float* __restrict__ A2,
    const short* __restrict__ Bhi, const short* __restrict__ Blo,
    const float* __restrict__ bias, float* __restrict__ C,
    int M, int kc1, int kcT, int strideA1) {
    __shared__ short Ahi[128 * 72];
    __shared__ short Alo[128 * 72];
    int tid = threadIdx.x;
    int rBase = blockIdx.x * 128;
    int wv = tid >> 6, lane = tid & 63;
    int rowHalf = wv >> 1, colHalf = wv & 1;
    int quad = lane >> 4, l15 = lane & 15;

    f32x4 acc[4][4];
#pragma unroll
    for (int a = 0; a < 4; a++)
#pragma unroll
        for (int b = 0; b < 4; b++) acc[a][b] = (f32x4)(0.f);

    for (int c = 0; c < kcT; c++) {
        const float* Asrc;
        int kOff, strideA;
        if (c < kc1) { Asrc = A1; kOff = c * 64; strideA = strideA1; }
        else { Asrc = A2; kOff = (c - kc1) * 64; strideA = 128; }

        __syncthreads();  // protect LDS from previous iteration's readers
#pragma unroll
        for (int q8 = 0; q8 < 8; q8++) {
            int slot = q8 * 256 + tid;
            int r = slot >> 4, k4 = slot & 15;
            float4 v = make_float4(0.f, 0.f, 0.f, 0.f);
            int gr = rBase + r;
            if (gr < M) v = *(const float4*)(Asrc + (size_t)gr * strideA + kOff + k4 * 4);
            unsigned int ux = __builtin_bit_cast(unsigned int, v.x);
            unsigned int uy = __builtin_bit_cast(unsigned int, v.y);
            unsigned int uz = __builtin_bit_cast(unsigned int, v.z);
            unsigned int uw = __builtin_bit_cast(unsigned int, v.w);
            unsigned int hx = ux >> 16, hy = uy >> 16, hz = uz >> 16, hw = uw >> 16;
            float fx = __builtin_bit_cast(float, ux & 0xffff0000u);
            float fy = __builtin_bit_cast(float, uy & 0xffff0000u);
            float fz = __builtin_bit_cast(float, uz & 0xffff0000u);
            float fw = __builtin_bit_cast(float, uw & 0xffff0000u);
            unsigned int lx = __builtin_bit_cast(unsigned int, v.x - fx) >> 16;
            unsigned int ly = __builtin_bit_cast(unsigned int, v.y - fy) >> 16;
            unsigned int lz = __builtin_bit_cast(unsigned int, v.z - fz) >> 16;
            unsigned int lw = __builtin_bit_cast(unsigned int, v.w - fw) >> 16;
            uint2 ph = make_uint2(hx | (hy << 16), hz | (hw << 16));
            uint2 pl = make_uint2(lx | (ly << 16), lz | (lw << 16));
            *(uint2*)(Ahi + r * 72 + k4 * 4) = ph;
            *(uint2*)(Alo + r * 72 + k4 * 4) = pl;
        }
        __syncthreads();

#pragma unroll
        for (int s = 0; s < 2; s++) {
            short8 ah[4], al[4];
#pragma unroll
            for (int rb = 0; rb < 4; rb++) {
                int m = rowHalf * 64 + rb * 16 + l15;
                ah[rb] = *(const short8*)(Ahi + m * 72 + s * 32 + quad * 8);
                al[rb] = *(const short8*)(Alo + m * 72 + s * 32 + quad * 8);
            }
#pragma unroll
            for (int cg = 0; cg < 4; cg++) {
                int G = colHalf * 4 + cg;
                size_t bo = ((((size_t)(c * 2 + s)) * 8 + G) * 64 + lane) * 8;
                short8 bh = *(const short8*)(Bhi + bo);
                short8 bl = *(const short8*)(Blo + bo);
#pragma unroll
                for (int rb = 0; rb < 4; rb++) {
                    acc[rb][cg] = __builtin_amdgcn_mfma_f32_16x16x32_bf16(ah[rb], bh, acc[rb][cg], 0, 0, 0);
                    acc[rb][cg] = __builtin_amdgcn_mfma_f32_16x16x32_bf16(al[rb], bh, acc[rb][cg], 0, 0, 0);
                    acc[rb][cg] = __builtin_amdgcn_mfma_f32_16x16x32_bf16(ah[rb], bl, acc[rb][cg], 0, 0, 0);
                }
            }
        }
    }

#pragma unroll
    for (int cg = 0; cg < 4; cg++) {
        int col = colHalf * 64 + cg * 16 + l15;
        float bv = bias ? bias[col] : 0.f;
#pragma unroll
        for (int rb = 0; rb < 4; rb++) {
#pragma unroll
            for (int r = 0; r < 4; r++) {
                int row = rBase + rowHalf * 64 + rb * 16 + quad * 4 + r;
                if (row < M) C[(size_t)row * HH + col] = acc[rb][cg][r] + bv;
            }
        }
    }
}

// ---------------- Aggregations (1 wave per node) ----------------

__global__ void k_gcn_agg(const float* __restrict__ h, const int* __restrict__ row_start,
                          const int* __restrict__ deg, const int* __restrict__ csr,
                          const float* __restrict__ dinv, const float* __restrict__ b1,
                          float* __restrict__ out) {
    int n = blockIdx.x * 4 + (threadIdx.x >> 6);
    if (n >= NN) return;
    int lane = threadIdx.x & 63;
    const float2* hp = (const float2*)h;
    float di = dinv[n];
    float2 hv = hp[(size_t)n * 64 + lane];
    float ws = di * di;
    float2 acc;
    acc.x = hv.x * ws;
    acc.y = hv.y * ws;
    int s0 = row_start[n], cnt = deg[n];
    for (int i = 0; i < cnt; i++) {
        int s = csr[s0 + i];
        float w = dinv[s] * di;
        float2 v = hp[(size_t)s * 64 + lane];
        acc.x += v.x * w;
        acc.y += v.y * w;
    }
    float2 bb = ((const float2*)b1)[lane];
    acc.x += bb.x;
    acc.y += bb.y;
    ((float2*)out)[(size_t)n * 64 + lane] = acc;
}

__global__ void k_sage_agg(const float* __restrict__ h, const int* __restrict__ row_start,
                           const int* __restrict__ deg, const int* __restrict__ csr,
                           const float* __restrict__ inv_sage, float* __restrict__ out) {
    int n = blockIdx.x * 4 + (threadIdx.x >> 6);
    if (n >= NN) return;
    int lane = threadIdx.x & 63;
    const float2* hp = (const float2*)h;
    float2 acc = make_float2(0.f, 0.f);
    int s0 = row_start[n], cnt = deg[n];
    for (int i = 0; i < cnt; i++) {
        int s = csr[s0 + i];
        float2 v = hp[(size_t)s * 64 + lane];
        acc.x += v.x;
        acc.y += v.y;
    }
    float sc = inv_sage[n];
    acc.x *= sc;
    acc.y *= sc;
    ((float2*)out)[(size_t)n * 64 + lane] = acc;
}

// ---- GAT precomputes ----

__global__ void k_att_fold(const float* __restrict__ W3, const float* __restrict__ att_src,
                           const float* __restrict__ att_dst, float* __restrict__ wsrc,
                           float* __restrict__ wdst) {
    int tid = threadIdx.x;  // 384 threads: h = tid>>7, k = tid&127
    int h = tid >> 7, k = tid & 127;
    float s1 = 0.f, s2 = 0.f;
    const float* wrow = W3 + (size_t)k * 384 + h * 128;
    const float* as = att_src + h * 128;
    const float* ad = att_dst + h * 128;
    for (int j = 0; j < 128; j++) {
        float wv = wrow[j];
        s1 += wv * as[j];
        s2 += wv * ad[j];
    }
    wsrc[tid] = s1;
    wdst[tid] = s2;
}

// W3p[(h*128+k)*128 + c] = W3[k*384 + h*128 + c] / 3
__global__ void k_w3t(const float* __restrict__ W3, float* __restrict__ W3p) {
    int i = blockIdx.x * 256 + threadIdx.x;
    if (i >= 384 * 128) return;
    int h = i >> 14, k = (i >> 7) & 127, c = i & 127;
    W3p[i] = W3[(size_t)k * 384 + h * 128 + c] * (1.f / 3.f);
}

__global__ void k_att(const float* __restrict__ h2, const float* __restrict__ wsrc,
                      const float* __restrict__ wdst, float* __restrict__ asrc,
                      float* __restrict__ adst) {
    int n = blockIdx.x * 4 + (threadIdx.x >> 6);
    if (n >= NN) return;
    int lane = threadIdx.x & 63;
    const float2* hp = (const float2*)h2;
    const float2* ws2 = (const float2*)wsrc;
    const float2* wd2 = (const float2*)wdst;
    float2 hv = hp[(size_t)n * 64 + lane];
#pragma unroll
    for (int hd = 0; hd < 3; hd++) {
        float2 a = ws2[hd * 64 + lane];
        float2 b = wd2[hd * 64 + lane];
        float s1 = hv.x * a.x + hv.y * a.y;
        float s2 = hv.x * b.x + hv.y * b.y;
        for (int o = 32; o > 0; o >>= 1) {
            s1 += __shfl_down(s1, o, 64);
            s2 += __shfl_down(s2, o, 64);
        }
        if (lane == 0) {
            asrc[n * 3 + hd] = s1;
            adst[n * 3 + hd] = s2;
        }
    }
}

__device__ __forceinline__ float lrelu(float a) { return fmaxf(a, SLOPE * a); }

__global__ void k_gat_agg(const float* __restrict__ h2, const int* __restrict__ row_start,
                          const int* __restrict__ deg, const int* __restrict__ csr,
                          const float* __restrict__ asrc, const float* __restrict__ adst,
                          float* __restrict__ agg) {
    int n = blockIdx.x * 4 + (threadIdx.x >> 6);
    if (n >= NN) return;
    int lane = threadIdx.x & 63;
    const float2* hp = (const float2*)h2;
    float ad0 = adst[n * 3 + 0], ad1 = adst[n * 3 + 1], ad2 = adst[n * 3 + 2];
    float m0 = lrelu(asrc[n * 3 + 0] + ad0);
    float m1 = lrelu(asrc[n * 3 + 1] + ad1);
    float m2 = lrelu(asrc[n * 3 + 2] + ad2);
    float l0 = 1.f, l1 = 1.f, l2 = 1.f;
    float2 hv = hp[(size_t)n * 64 + lane];
    float2 a0 = hv, a1 = hv, a2 = hv;
    int s0r = row_start[n], cnt = deg[n];
    for (int i = 0; i < cnt; i++) {
        int s = csr[s0r + i];
        float e0 = lrelu(asrc[s * 3 + 0] + ad0);
        float e1 = lrelu(asrc[s * 3 + 1] + ad1);
        float e2 = lrelu(asrc[s * 3 + 2] + ad2);
        float2 v = hp[(size_t)s * 64 + lane];
        float mn, sc, w;
        mn = fmaxf(m0, e0); sc = __expf(m0 - mn); w = __expf(e0 - mn);
        l0 = l0 * sc + w; a0.x = a0.x * sc + w * v.x; a0.y = a0.y * sc + w * v.y; m0 = mn;
        mn = fmaxf(m1, e1); sc = __expf(m1 - mn); w = __expf(e1 - mn);
        l1 = l1 * sc + w; a1.x = a1.x * sc + w * v.x; a1.y = a1.y * sc + w * v.y; m1 = mn;
        mn = fmaxf(m2, e2); sc = __expf(m2 - mn); w = __expf(e2 - mn);
        l2 = l2 * sc + w; a2.x = a2.x * sc + w * v.x; a2.y = a2.y * sc + w * v.y; m2 = mn;
    }
    float r0 = 1.f / l0, r1 = 1.f / l1, r2 = 1.f / l2;
    float2* op = (float2*)agg + (size_t)n * 192;
    op[lane] = make_float2(a0.x * r0, a0.y * r0);
    op[64 + lane] = make_float2(a1.x * r1, a1.y * r1);
    op[128 + lane] = make_float2(a2.x * r2, a2.y * r2);
}

// ---------------- BatchNorm + ELU ----------------

__global__ void k_bn_stats(const float* __restrict__ h, float* __restrict__ sums) {
    int f = threadIdx.x;  // 128 threads
    int rows_per = (NN + gridDim.x - 1) / gridDim.x;
    int r0 = blockIdx.x * rows_per;
    int r1 = r0 + rows_per;
    if (r1 > NN) r1 = NN;
    float s = 0.f, sq = 0.f;
    for (int r = r0; r < r1; r++) {
        float v = h[(size_t)r * 128 + f];
        s += v;
        sq += v * v;
    }
    atomicAdd(&sums[f], s);
    atomicAdd(&sums[128 + f], sq);
}

__global__ void k_bn_fin(const float* __restrict__ sums, const float* __restrict__ gamma,
                         const float* __restrict__ beta, float* __restrict__ coef) {
    int f = threadIdx.x;
    float mu = sums[f] * (1.0f / NN);
    float var = sums[128 + f] * (1.0f / NN) - mu * mu;
    float rs = rsqrtf(var + EPSV);
    float sc = rs * gamma[f];
    coef[f] = sc;
    coef[128 + f] = beta[f] - mu * sc;
}

__device__ __forceinline__ float elu1(float x) { return x > 0.f ? x : (__expf(x) - 1.f); }

__global__ void k_bn_elu(float* __restrict__ h, const float* __restrict__ coef) {
    int i = blockIdx.x * 256 + threadIdx.x;
    if (i >= NN * 32) return;
    int f4 = (i & 31) << 2;
    float4 v = ((float4*)h)[i];
    float4 sc = *(const float4*)(coef + f4);
    float4 sh = *(const float4*)(coef + 128 + f4);
    v.x = elu1(v.x * sc.x + sh.x);
    v.y = elu1(v.y * sc.y + sh.y);
    v.z = elu1(v.z * sc.z + sh.z);
    v.w = elu1(v.w * sc.w + sh.w);
    ((float4*)h)[i] = v;
}

// ---------------- Pool (two-stage, parallel) + classifier ----------------

#define POOL_BLOCKS 800

__global__ void k_pool_partial(const float* __restrict__ h, const int* __restrict__ batch,
                               float* __restrict__ pool, float* __restrict__ cntf) {
    const int RP = (NN + POOL_BLOCKS - 1) / POOL_BLOCKS;  // 63
    int r0 = blockIdx.x * RP;
    int r1 = r0 + RP;
    if (r1 > NN) r1 = NN;
    if (r0 >= r1) return;
    int f = threadIdx.x;  // 128 threads (feature)
    int g = batch[r0];
    float s = 0.f, c = 0.f;
    for (int r = r0; r < r1; r++) {
        int gr = batch[r];
        if (gr != g) {
            atomicAdd(&pool[g * 128 + f], s);
            if (f == 0) atomicAdd(&cntf[g], c);
            s = 0.f; c = 0.f; g = gr;
        }
        s += h[(size_t)r * 128 + f];
        c += 1.f;
    }
    atomicAdd(&pool[g * 128 + f], s);
    if (f == 0) atomicAdd(&cntf[g], c);
}

__global__ void k_pool_fin(const float* __restrict__ pool, const float* __restrict__ cntf,
                           float* __restrict__ out) {
    int g = blockIdx.x;  // GG blocks x 128 threads
    int f = threadIdx.x;
    float c = cntf[g];
    out[g * 128 + f] = pool[g * 128 + f] / fmaxf(c, 1.f);
}

__global__ void k_logits(const float* __restrict__ pooled, const float* __restrict__ Wc,
                         const float* __restrict__ bc, float* __restrict__ out) {
    int i = blockIdx.x * 256 + threadIdx.x;
    if (i >= GG * CC) return;
    int g = i / CC, c = i % CC;
    float s = bc[c];
    for (int k = 0; k < 128; k++) s += pooled[g * 128 + k] * Wc[k * CC + c];
    out[i] = s;
}

// ---------------- launch ----------------

extern "C" void kernel_launch(void* const* d_in, const int* in_sizes, int n_in,
                              void* d_out, int out_size, void* d_ws, size_t ws_size,
                              hipStream_t stream) {
    const float* x = (const float*)d_in[0];
    const int* ei = (const int*)d_in[1];
    const int* batch = (const int*)d_in[2];
    const float* W1 = (const float*)d_in[3];
    const float* b1 = (const float*)d_in[4];
    const float* gamma1 = (const float*)d_in[5];
    const float* beta1 = (const float*)d_in[6];
    const float* Wl = (const float*)d_in[7];
    const float* bl = (const float*)d_in[8];
    const float* Wr = (const float*)d_in[9];
    const float* gamma2 = (const float*)d_in[10];
    const float* beta2 = (const float*)d_in[11];
    const float* W3 = (const float*)d_in[12];
    const float* att_src = (const float*)d_in[13];
    const float* att_dst = (const float*)d_in[14];
    const float* b3 = (const float*)d_in[15];
    const float* gamma3 = (const float*)d_in[16];
    const float* beta3 = (const float*)d_in[17];
    const float* Wc = (const float*)d_in[18];
    const float* bc = (const float*)d_in[19];

    char* w = (char*)d_ws;
    const size_t SZ_NH = (size_t)NN * 128 * 4;  // 25.6 MB
    float* bufA = (float*)(w + 0);
    float* bufB = (float*)(w + SZ_NH);
    float* bufC = (float*)(w + 2 * SZ_NH);
    float* aggD = (float*)(w + 3 * SZ_NH);            // N x 384
    size_t o = 3 * SZ_NH + (size_t)NN * 384 * 4;
    int* csr = (int*)(w + o); o += (size_t)EE * 4;
    int* deg = (int*)(w + o); o += (size_t)NN * 4;
    int* row_start = (int*)(w + o); o += (size_t)NN * 4;
    int* cursor = (int*)(w + o); o += (size_t)NN * 4;
    float* dinv = (float*)(w + o); o += (size_t)NN * 4;
    float* inv_sage = (float*)(w + o); o += (size_t)NN * 4;
    float* asrc = (float*)(w + o); o += (size_t)NN * 3 * 4;
    float* adst = (float*)(w + o); o += (size_t)NN * 3 * 4;
    float* bn_sums = (float*)(w + o); o += 3 * 256 * 4;
    float* bn_coef = (float*)(w + o); o += 256 * 4;
    int* blk = (int*)(w + o); o += 1024;
    float* poolacc = (float*)(w + o); o += (size_t)GG * 128 * 4;
    float* cntf = (float*)(w + o); o += (size_t)GG * 4;
    float* wsrc = (float*)(w + o); o += 384 * 4;
    float* wdst = (float*)(w + o); o += 384 * 4;
    float* W3p = (float*)(w + o); o += (size_t)384 * 128 * 4;
    short* w1hi = (short*)(w + o); o += (size_t)128 * 128 * 2;
    short* w1lo = (short*)(w + o); o += (size_t)128 * 128 * 2;
    short* wshi = (short*)(w + o); o += (size_t)256 * 128 * 2;
    short* wslo = (short*)(w + o); o += (size_t)256 * 128 * 2;
    short* w3hi = (short*)(w + o); o += (size_t)384 * 128 * 2;
    short* w3lo = (short*)(w + o); o += (size_t)384 * 128 * 2;

    float* outp = (float*)d_out;

    const int NB_SCAN = (NN + 255) / 256;  // 196
    const int EB = (EE + 255) / 256;
    const int NW4 = (NN + 3) / 4;           // wave-per-node kernels, 4 waves/block
    const int GB = (NN + 127) / 128;        // MFMA gemm blocks = 391

    hipMemsetAsync(deg, 0, (size_t)NN * 4, stream);
    hipMemsetAsync(bn_sums, 0, 3 * 256 * 4, stream);
    hipMemsetAsync(poolacc, 0, ((size_t)GG * 128 + GG) * 4, stream);

    k_count_deg<<<EB, 256, 0, stream>>>(ei, deg);
    k_scan1<<<NB_SCAN, 256, 0, stream>>>(deg, row_start, blk);
    k_scan2<<<1, 256, 0, stream>>>(blk, NB_SCAN);
    k_scan3<<<NB_SCAN, 256, 0, stream>>>(row_start, blk, deg, cursor, dinv, inv_sage);
    k_fill<<<EB, 256, 0, stream>>>(ei, cursor, csr);

    // Weight prep (tiny): fold att vectors, transpose W3, bf16-split all GEMM weights
    k_att_fold<<<1, 384, 0, stream>>>(W3, att_src, att_dst, wsrc, wdst);
    k_w3t<<<(384 * 128 + 255) / 256, 256, 0, stream>>>(W3, W3p);
    k_prep_w<<<64, 256, 0, stream>>>(W1, w1hi, w1lo, 128 * 128, 0);
    k_prep_w<<<64, 256, 0, stream>>>(Wl, wshi, wslo, 128 * 128, 0);
    k_prep_w<<<64, 256, 0, stream>>>(Wr, wshi, wslo, 128 * 128, 2);
    k_prep_w<<<192, 256, 0, stream>>>(W3p, w3hi, w3lo, 384 * 128, 0);

    // Layer 1: GCN
    k_gemm_mfma<<<GB, 256, 0, stream>>>(x, nullptr, w1hi, w1lo, nullptr, bufB, NN, 2, 2, 128);
    k_gcn_agg<<<NW4, 256, 0, stream>>>(bufB, row_start, deg, csr, dinv, b1, bufA);
    k_bn_stats<<<1024, 128, 0, stream>>>(bufA, bn_sums);
    k_bn_fin<<<1, 128, 0, stream>>>(bn_sums, gamma1, beta1, bn_coef);
    k_bn_elu<<<(NN * 32 + 255) / 256, 256, 0, stream>>>(bufA, bn_coef);

    // Layer 2: SAGE (fused K=256: [agg | h1'] @ [Wl; Wr] + bl)
    k_sage_agg<<<NW4, 256, 0, stream>>>(bufA, row_start, deg, csr, inv_sage, bufB);
    k_gemm_mfma<<<GB, 256, 0, stream>>>(bufB, bufA, wshi, wslo, bl, bufC, NN, 2, 4, 128);
    k_bn_stats<<<1024, 128, 0, stream>>>(bufC, bn_sums + 256);
    k_bn_fin<<<1, 128, 0, stream>>>(bn_sums + 256, gamma2, beta2, bn_coef);
    k_bn_elu<<<(NN * 32 + 255) / 256, 256, 0, stream>>>(bufC, bn_coef);

    // Layer 3: GAT (aggregate-then-transform)
    k_att<<<NW4, 256, 0, stream>>>(bufC, wsrc, wdst, asrc, adst);
    k_gat_agg<<<NW4, 256, 0, stream>>>(bufC, row_start, deg, csr, asrc, adst, aggD);
    k_gemm_mfma<<<GB, 256, 0, stream>>>(aggD, nullptr, w3hi, w3lo, b3, bufA, NN, 6, 6, 384);
    k_bn_stats<<<1024, 128, 0, stream>>>(bufA, bn_sums + 512);
    k_bn_fin<<<1, 128, 0, stream>>>(bn_sums + 512, gamma3, beta3, bn_coef);
    k_bn_elu<<<(NN * 32 + 255) / 256, 256, 0, stream>>>(bufA, bn_coef);

    // Pool + classifier
    k_pool_partial<<<POOL_BLOCKS, 128, 0, stream>>>(bufA, batch, poolacc, cntf);
    k_pool_fin<<<GG, 128, 0, stream>>>(poolacc, cntf, outp);
    k_logits<<<(GG * CC + 255) / 256, 256, 0, stream>>>(outp, Wc, bc, outp + GG * HH);
}

// Round 5
// 673.990 us; speedup vs baseline: 1.4736x; 1.0036x over previous
//
#include <hip/hip_runtime.h>
#include <math.h>

#define NN 50000
#define EE 500000
#define HH 128
#define NHEADS 3
#define CC 10
#define GG 64
#define EPSV 1e-5f
#define SLOPE 0.2f

typedef __attribute__((ext_vector_type(8))) short short8;
typedef __attribute__((ext_vector_type(4))) float f32x4;

// ---------------- CSR build ----------------

__global__ void k_count_deg(const int* __restrict__ ei, int* __restrict__ deg) {
    int e = blockIdx.x * 256 + threadIdx.x;
    if (e < EE) atomicAdd(&deg[ei[EE + e]], 1);
}

__global__ void k_scan1(const int* __restrict__ deg, int* __restrict__ row_start,
                        int* __restrict__ blk) {
    __shared__ int s[256];
    int i = blockIdx.x * 256 + threadIdx.x;
    int v = (i < NN) ? deg[i] : 0;
    s[threadIdx.x] = v;
    __syncthreads();
    for (int o = 1; o < 256; o <<= 1) {
        int t = (threadIdx.x >= o) ? s[threadIdx.x - o] : 0;
        __syncthreads();
        s[threadIdx.x] += t;
        __syncthreads();
    }
    if (i < NN) row_start[i] = s[threadIdx.x] - v;  // exclusive
    if (threadIdx.x == 255) blk[blockIdx.x] = s[255];
}

__global__ void k_scan2(int* __restrict__ blk, int nb) {
    __shared__ int s[256];
    int v = (threadIdx.x < nb) ? blk[threadIdx.x] : 0;
    s[threadIdx.x] = v;
    __syncthreads();
    for (int o = 1; o < 256; o <<= 1) {
        int t = (threadIdx.x >= o) ? s[threadIdx.x - o] : 0;
        __syncthreads();
        s[threadIdx.x] += t;
        __syncthreads();
    }
    if (threadIdx.x < nb) blk[threadIdx.x] = s[threadIdx.x] - v;  // exclusive
}

__global__ void k_scan3(int* __restrict__ row_start, const int* __restrict__ blk,
                        const int* __restrict__ deg, int* __restrict__ cursor,
                        float* __restrict__ dinv, float* __restrict__ inv_sage) {
    int i = blockIdx.x * 256 + threadIdx.x;
    if (i < NN) {
        int rs = row_start[i] + blk[blockIdx.x];
        row_start[i] = rs;
        cursor[i] = rs;
        int d = deg[i];
        dinv[i] = rsqrtf((float)(d + 1));
        inv_sage[i] = 1.0f / (float)(d > 1 ? d : 1);
    }
}

__global__ void k_fill(const int* __restrict__ ei, int* __restrict__ cursor,
                       int* __restrict__ csr_src) {
    int e = blockIdx.x * 256 + threadIdx.x;
    if (e < EE) {
        int d = ei[EE + e];
        int p = atomicAdd(&cursor[d], 1);
        csr_src[p] = ei[e];
    }
}

// ---------------- Weight prep: fp32 -> fragment-ordered bf16 hi/lo ----------------
// element (k,n): c=k>>6, s=(k>>5)&1, quad=(k>>3)&3, j=k&7, G=n>>4, l=quad*16+(n&15)
// dst = ((((c*2+s)*8 + G)*64) + l)*8 + j

__device__ __forceinline__ void split_store(float x, size_t dst, short* hi, short* lo) {
    unsigned int ux = __builtin_bit_cast(unsigned int, x);
    unsigned short hx = (unsigned short)(ux >> 16);
    float fx = __builtin_bit_cast(float, ux & 0xffff0000u);
    unsigned short lx = (unsigned short)(__builtin_bit_cast(unsigned int, x - fx) >> 16);
    hi[dst] = (short)hx;
    lo[dst] = (short)lx;
}

__global__ void k_prep_w(const float* __restrict__ W, short* __restrict__ hi,
                         short* __restrict__ lo, int kelems, int cBase) {
    int i = blockIdx.x * 256 + threadIdx.x;
    if (i >= kelems) return;
    int k = i >> 7, n = i & 127;
    int c = (k >> 6) + cBase;
    int s = (k >> 5) & 1, quad = (k >> 3) & 3, j = k & 7;
    int G = n >> 4, l = quad * 16 + (n & 15);
    size_t dst = ((((size_t)(c * 2 + s)) * 8 + G) * 64 + l) * 8 + j;
    split_store(W[i], dst, hi, lo);
}

// W3 fragment prep with built-in transpose + /3: Bp[k'=h*128+kk][n] = W3[kk*384+h*128+n]/3
__global__ void k_prep_w3(const float* __restrict__ W3, short* __restrict__ hi,
                          short* __restrict__ lo) {
    int i = blockIdx.x * 256 + threadIdx.x;
    if (i >= 384 * 128) return;
    int k = i >> 7, n = i & 127;
    int h = k >> 7, kk = k & 127;
    float x = W3[(size_t)kk * 384 + h * 128 + n] * (1.f / 3.f);
    int c = k >> 6, s = (k >> 5) & 1, quad = (k >> 3) & 3, j = k & 7;
    int G = n >> 4, l = quad * 16 + (n & 15);
    size_t dst = ((((size_t)(c * 2 + s)) * 8 + G) * 64 + l) * 8 + j;
    split_store(x, dst, hi, lo);
}

// ---------------- MFMA GEMM (split-bf16, C = [A1|A2] @ B + bias) ----------------

__global__ __launch_bounds__(256) void k_gemm_mfma(
    const float* __restrict__ A1, const float* __restrict__ A2,
    const short* __restrict__ Bhi, const short* __restrict__ Blo,
    const float* __restrict__ bias, float* __restrict__ C,
    int M, int kc1, int kcT, int strideA1) {
    __shared__ short Ahi[128 * 72];
    __shared__ short Alo[128 * 72];
    int tid = threadIdx.x;
    int rBase = blockIdx.x * 128;
    int wv = tid >> 6, lane = tid & 63;
    int rowHalf = wv >> 1, colHalf = wv & 1;
    int quad = lane >> 4, l15 = lane & 15;

    f32x4 acc[4][4];
#pragma unroll
    for (int a = 0; a < 4; a++)
#pragma unroll
        for (int b = 0; b < 4; b++) acc[a][b] = (f32x4)(0.f);

    for (int c = 0; c < kcT; c++) {
        const float* Asrc;
        int kOff, strideA;
        if (c < kc1) { Asrc = A1; kOff = c * 64; strideA = strideA1; }
        else { Asrc = A2; kOff = (c - kc1) * 64; strideA = 128; }

        __syncthreads();
#pragma unroll
        for (int q8 = 0; q8 < 8; q8++) {
            int slot = q8 * 256 + tid;
            int r = slot >> 4, k4 = slot & 15;
            float4 v = make_float4(0.f, 0.f, 0.f, 0.f);
            int gr = rBase + r;
            if (gr < M) v = *(const float4*)(Asrc + (size_t)gr * strideA + kOff + k4 * 4);
            unsigned int ux = __builtin_bit_cast(unsigned int, v.x);
            unsigned int uy = __builtin_bit_cast(unsigned int, v.y);
            unsigned int uz = __builtin_bit_cast(unsigned int, v.z);
            unsigned int uw = __builtin_bit_cast(unsigned int, v.w);
            unsigned int hx = ux >> 16, hy = uy >> 16, hz = uz >> 16, hw = uw >> 16;
            float fx = __builtin_bit_cast(float, ux & 0xffff0000u);
            float fy = __builtin_bit_cast(float, uy & 0xffff0000u);
            float fz = __builtin_bit_cast(float, uz & 0xffff0000u);
            float fw = __builtin_bit_cast(float, uw & 0xffff0000u);
            unsigned int lx = __builtin_bit_cast(unsigned int, v.x - fx) >> 16;
            unsigned int ly = __builtin_bit_cast(unsigned int, v.y - fy) >> 16;
            unsigned int lz = __builtin_bit_cast(unsigned int, v.z - fz) >> 16;
            unsigned int lw = __builtin_bit_cast(unsigned int, v.w - fw) >> 16;
            uint2 ph = make_uint2(hx | (hy << 16), hz | (hw << 16));
            uint2 pl = make_uint2(lx | (ly << 16), lz | (lw << 16));
            *(uint2*)(Ahi + r * 72 + k4 * 4) = ph;
            *(uint2*)(Alo + r * 72 + k4 * 4) = pl;
        }
        __syncthreads();

#pragma unroll
        for (int s = 0; s < 2; s++) {
            short8 ah[4], al[4];
#pragma unroll
            for (int rb = 0; rb < 4; rb++) {
                int m = rowHalf * 64 + rb * 16 + l15;
                ah[rb] = *(const short8*)(Ahi + m * 72 + s * 32 + quad * 8);
                al[rb] = *(const short8*)(Alo + m * 72 + s * 32 + quad * 8);
            }
#pragma unroll
            for (int cg = 0; cg < 4; cg++) {
                int G = colHalf * 4 + cg;
                size_t bo = ((((size_t)(c * 2 + s)) * 8 + G) * 64 + lane) * 8;
                short8 bh = *(const short8*)(Bhi + bo);
                short8 bl = *(const short8*)(Blo + bo);
#pragma unroll
                for (int rb = 0; rb < 4; rb++) {
                    acc[rb][cg] = __builtin_amdgcn_mfma_f32_16x16x32_bf16(ah[rb], bh, acc[rb][cg], 0, 0, 0);
                    acc[rb][cg] = __builtin_amdgcn_mfma_f32_16x16x32_bf16(al[rb], bh, acc[rb][cg], 0, 0, 0);
                    acc[rb][cg] = __builtin_amdgcn_mfma_f32_16x16x32_bf16(ah[rb], bl, acc[rb][cg], 0, 0, 0);
                }
            }
        }
    }

#pragma unroll
    for (int cg = 0; cg < 4; cg++) {
        int col = colHalf * 64 + cg * 16 + l15;
        float bv = bias ? bias[col] : 0.f;
#pragma unroll
        for (int rb = 0; rb < 4; rb++) {
#pragma unroll
            for (int r = 0; r < 4; r++) {
                int row = rBase + rowHalf * 64 + rb * 16 + quad * 4 + r;
                if (row < M) C[(size_t)row * HH + col] = acc[rb][cg][r] + bv;
            }
        }
    }
}

// ---------------- Aggregations (1 wave per node) ----------------

__global__ void k_gcn_agg(const float* __restrict__ h, const int* __restrict__ row_start,
                          const int* __restrict__ deg, const int* __restrict__ csr,
                          const float* __restrict__ dinv, const float* __restrict__ b1,
                          float* __restrict__ out) {
    int n = blockIdx.x * 4 + (threadIdx.x >> 6);
    if (n >= NN) return;
    int lane = threadIdx.x & 63;
    const float2* hp = (const float2*)h;
    float di = dinv[n];
    float2 hv = hp[(size_t)n * 64 + lane];
    float ws = di * di;
    float2 acc;
    acc.x = hv.x * ws;
    acc.y = hv.y * ws;
    int s0 = row_start[n], cnt = deg[n];
    for (int i = 0; i < cnt; i++) {
        int s = csr[s0 + i];
        float w = dinv[s] * di;
        float2 v = hp[(size_t)s * 64 + lane];
        acc.x += v.x * w;
        acc.y += v.y * w;
    }
    float2 bb = ((const float2*)b1)[lane];
    acc.x += bb.x;
    acc.y += bb.y;
    ((float2*)out)[(size_t)n * 64 + lane] = acc;
}

__global__ void k_sage_agg(const float* __restrict__ h, const int* __restrict__ row_start,
                           const int* __restrict__ deg, const int* __restrict__ csr,
                           const float* __restrict__ inv_sage, float* __restrict__ out) {
    int n = blockIdx.x * 4 + (threadIdx.x >> 6);
    if (n >= NN) return;
    int lane = threadIdx.x & 63;
    const float2* hp = (const float2*)h;
    float2 acc = make_float2(0.f, 0.f);
    int s0 = row_start[n], cnt = deg[n];
    for (int i = 0; i < cnt; i++) {
        int s = csr[s0 + i];
        float2 v = hp[(size_t)s * 64 + lane];
        acc.x += v.x;
        acc.y += v.y;
    }
    float sc = inv_sage[n];
    acc.x *= sc;
    acc.y *= sc;
    ((float2*)out)[(size_t)n * 64 + lane] = acc;
}

// ---- GAT precomputes ----

__global__ void k_att_fold(const float* __restrict__ W3, const float* __restrict__ att_src,
                           const float* __restrict__ att_dst, float* __restrict__ wsrc,
                           float* __restrict__ wdst) {
    int tid = threadIdx.x;  // 384 threads: h = tid>>7, k = tid&127
    int h = tid >> 7, k = tid & 127;
    float s1 = 0.f, s2 = 0.f;
    const float* wrow = W3 + (size_t)k * 384 + h * 128;
    const float* as = att_src + h * 128;
    const float* ad = att_dst + h * 128;
    for (int j = 0; j < 128; j++) {
        float wv = wrow[j];
        s1 += wv * as[j];
        s2 += wv * ad[j];
    }
    wsrc[tid] = s1;
    wdst[tid] = s2;
}

__device__ __forceinline__ float lrelu(float a) { return fmaxf(a, SLOPE * a); }

// Per-node softmax over in-edges, lane-parallel. Writes normalized alpha per edge
// (float4: a0,a1,a2,-) and self-weight per node.
__global__ void k_alpha(const int* __restrict__ row_start, const int* __restrict__ deg,
                        const int* __restrict__ csr, const float* __restrict__ asrc,
                        const float* __restrict__ adst, float4* __restrict__ alphaE,
                        float4* __restrict__ aself) {
    int n = blockIdx.x * 4 + (threadIdx.x >> 6);
    if (n >= NN) return;
    int lane = threadIdx.x & 63;
    float ad0 = adst[n * 3 + 0], ad1 = adst[n * 3 + 1], ad2 = adst[n * 3 + 2];
    float es0 = lrelu(asrc[n * 3 + 0] + ad0);
    float es1 = lrelu(asrc[n * 3 + 1] + ad1);
    float es2 = lrelu(asrc[n * 3 + 2] + ad2);
    int s0 = row_start[n], cnt = deg[n];
    float m0 = es0, m1 = es1, m2 = es2;
    // pass 1: gather logits, stash raw e, butterfly-max
    for (int base = 0; base < cnt; base += 64) {
        int i2 = base + lane;
        float e0 = -3e38f, e1 = -3e38f, e2 = -3e38f;
        if (i2 < cnt) {
            int s = csr[s0 + i2];
            e0 = lrelu(asrc[s * 3 + 0] + ad0);
            e1 = lrelu(asrc[s * 3 + 1] + ad1);
            e2 = lrelu(asrc[s * 3 + 2] + ad2);
            alphaE[s0 + i2] = make_float4(e0, e1, e2, 0.f);
        }
#pragma unroll
        for (int o = 32; o > 0; o >>= 1) {
            e0 = fmaxf(e0, __shfl_xor(e0, o, 64));
            e1 = fmaxf(e1, __shfl_xor(e1, o, 64));
            e2 = fmaxf(e2, __shfl_xor(e2, o, 64));
        }
        m0 = fmaxf(m0, e0); m1 = fmaxf(m1, e1); m2 = fmaxf(m2, e2);
    }
    // pass 2: denominators
    float l0 = __expf(es0 - m0), l1 = __expf(es1 - m1), l2 = __expf(es2 - m2);
    for (int base = 0; base < cnt; base += 64) {
        int i2 = base + lane;
        float w0 = 0.f, w1 = 0.f, w2 = 0.f;
        if (i2 < cnt) {
            float4 e = alphaE[s0 + i2];
            w0 = __expf(e.x - m0); w1 = __expf(e.y - m1); w2 = __expf(e.z - m2);
        }
#pragma unroll
        for (int o = 32; o > 0; o >>= 1) {
            w0 += __shfl_xor(w0, o, 64);
            w1 += __shfl_xor(w1, o, 64);
            w2 += __shfl_xor(w2, o, 64);
        }
        l0 += w0; l1 += w1; l2 += w2;
    }
    float r0 = 1.f / l0, r1 = 1.f / l1, r2 = 1.f / l2;
    if (lane == 0)
        aself[n] = make_float4(__expf(es0 - m0) * r0, __expf(es1 - m1) * r1,
                               __expf(es2 - m2) * r2, 0.f);
    // pass 3: write normalized alphas
    for (int base = 0; base < cnt; base += 64) {
        int i2 = base + lane;
        if (i2 < cnt) {
            float4 e = alphaE[s0 + i2];
            alphaE[s0 + i2] = make_float4(__expf(e.x - m0) * r0, __expf(e.y - m1) * r1,
                                          __expf(e.z - m2) * r2, 0.f);
        }
    }
}

// feature aggregation: uniform alpha loads + one 8B gather per edge per lane
__global__ void k_gat_agg2(const float* __restrict__ h2, const int* __restrict__ row_start,
                           const int* __restrict__ deg, const int* __restrict__ csr,
                           const float4* __restrict__ alphaE, const float4* __restrict__ aself,
                           float* __restrict__ agg) {
    int n = blockIdx.x * 4 + (threadIdx.x >> 6);
    if (n >= NN) return;
    int lane = threadIdx.x & 63;
    const float2* hp = (const float2*)h2;
    float4 asf = aself[n];
    float2 hv = hp[(size_t)n * 64 + lane];
    float2 a0 = make_float2(hv.x * asf.x, hv.y * asf.x);
    float2 a1 = make_float2(hv.x * asf.y, hv.y * asf.y);
    float2 a2 = make_float2(hv.x * asf.z, hv.y * asf.z);
    int s0 = row_start[n], cnt = deg[n];
    for (int i = 0; i < cnt; i++) {
        int s = csr[s0 + i];
        float4 al = alphaE[s0 + i];
        float2 v = hp[(size_t)s * 64 + lane];
        a0.x += al.x * v.x; a0.y += al.x * v.y;
        a1.x += al.y * v.x; a1.y += al.y * v.y;
        a2.x += al.z * v.x; a2.y += al.z * v.y;
    }
    float2* op = (float2*)agg + (size_t)n * 192;
    op[lane] = a0;
    op[64 + lane] = a1;
    op[128 + lane] = a2;
}

// ---------------- BatchNorm + ELU (coef computed inline from sums) ----------------

__global__ void k_bn_stats(const float* __restrict__ h, float* __restrict__ sums) {
    int f = threadIdx.x;  // 128 threads
    int rows_per = (NN + gridDim.x - 1) / gridDim.x;
    int r0 = blockIdx.x * rows_per;
    int r1 = r0 + rows_per;
    if (r1 > NN) r1 = NN;
    float s = 0.f, sq = 0.f;
    for (int r = r0; r < r1; r++) {
        float v = h[(size_t)r * 128 + f];
        s += v;
        sq += v * v;
    }
    atomicAdd(&sums[f], s);
    atomicAdd(&sums[128 + f], sq);
}

__device__ __forceinline__ float elu1(float x) { return x > 0.f ? x : (__expf(x) - 1.f); }

__device__ __forceinline__ float4 bn_apply4(float4 v, const float* sums,
                                            const float* gamma, const float* beta, int f4) {
    const float invN = 1.0f / NN;
    float4 s4 = *(const float4*)(sums + f4);
    float4 q4 = *(const float4*)(sums + 128 + f4);
    float4 g4 = *(const float4*)(gamma + f4);
    float4 b4 = *(const float4*)(beta + f4);
    float mx = s4.x * invN, my = s4.y * invN, mz = s4.z * invN, mw = s4.w * invN;
    float scx = rsqrtf(q4.x * invN - mx * mx + EPSV) * g4.x;
    float scy = rsqrtf(q4.y * invN - my * my + EPSV) * g4.y;
    float scz = rsqrtf(q4.z * invN - mz * mz + EPSV) * g4.z;
    float scw = rsqrtf(q4.w * invN - mw * mw + EPSV) * g4.w;
    v.x = elu1(v.x * scx + (b4.x - mx * scx));
    v.y = elu1(v.y * scy + (b4.y - my * scy));
    v.z = elu1(v.z * scz + (b4.z - mz * scz));
    v.w = elu1(v.w * scw + (b4.w - mw * scw));
    return v;
}

__global__ void k_bn_elu(float* __restrict__ h, const float* __restrict__ sums,
                         const float* __restrict__ gamma, const float* __restrict__ beta) {
    int i = blockIdx.x * 256 + threadIdx.x;  // NN*32 exactly
    int f4 = (i & 31) << 2;
    float4 v = bn_apply4(((float4*)h)[i], sums, gamma, beta, f4);
    ((float4*)h)[i] = v;
}

// layer-2 variant: also computes attention logits asrc/adst (row = 32 consecutive lanes)
__global__ void k_bn_elu_att(float* __restrict__ h, const float* __restrict__ sums,
                             const float* __restrict__ gamma, const float* __restrict__ beta,
                             const float* __restrict__ wsrc, const float* __restrict__ wdst,
                             float* __restrict__ asrc, float* __restrict__ adst) {
    int i = blockIdx.x * 256 + threadIdx.x;
    int fi = i & 31;
    int f4 = fi << 2;
    float4 v = bn_apply4(((float4*)h)[i], sums, gamma, beta, f4);
    ((float4*)h)[i] = v;
    const float4* ws4 = (const float4*)wsrc;
    const float4* wd4 = (const float4*)wdst;
    float d[6];
#pragma unroll
    for (int hd = 0; hd < 3; hd++) {
        float4 a = ws4[hd * 32 + fi];
        float4 b = wd4[hd * 32 + fi];
        d[hd] = v.x * a.x + v.y * a.y + v.z * a.z + v.w * a.w;
        d[3 + hd] = v.x * b.x + v.y * b.y + v.z * b.z + v.w * b.w;
    }
#pragma unroll
    for (int o = 16; o > 0; o >>= 1) {
#pragma unroll
        for (int j = 0; j < 6; j++) d[j] += __shfl_xor(d[j], o, 64);
    }
    if ((threadIdx.x & 31) == 0) {
        int r = i >> 5;
        asrc[r * 3 + 0] = d[0]; asrc[r * 3 + 1] = d[1]; asrc[r * 3 + 2] = d[2];
        adst[r * 3 + 0] = d[3]; adst[r * 3 + 1] = d[4]; adst[r * 3 + 2] = d[5];
    }
}

// ---------------- Pool (two-stage, parallel) + classifier ----------------

#define POOL_BLOCKS 800

__global__ void k_pool_partial(const float* __restrict__ h, const int* __restrict__ batch,
                               float* __restrict__ pool, float* __restrict__ cntf) {
    const int RP = (NN + POOL_BLOCKS - 1) / POOL_BLOCKS;  // 63
    int r0 = blockIdx.x * RP;
    int r1 = r0 + RP;
    if (r1 > NN) r1 = NN;
    if (r0 >= r1) return;
    int f = threadIdx.x;  // 128 threads (feature)
    int g = batch[r0];
    float s = 0.f, c = 0.f;
    for (int r = r0; r < r1; r++) {
        int gr = batch[r];
        if (gr != g) {
            atomicAdd(&pool[g * 128 + f], s);
            if (f == 0) atomicAdd(&cntf[g], c);
            s = 0.f; c = 0.f; g = gr;
        }
        s += h[(size_t)r * 128 + f];
        c += 1.f;
    }
    atomicAdd(&pool[g * 128 + f], s);
    if (f == 0) atomicAdd(&cntf[g], c);
}

__global__ void k_pool_fin(const float* __restrict__ pool, const float* __restrict__ cntf,
                           float* __restrict__ out) {
    int g = blockIdx.x;  // GG blocks x 128 threads
    int f = threadIdx.x;
    float c = cntf[g];
    out[g * 128 + f] = pool[g * 128 + f] / fmaxf(c, 1.f);
}

__global__ void k_logits(const float* __restrict__ pooled, const float* __restrict__ Wc,
                         const float* __restrict__ bc, float* __restrict__ out) {
    int i = blockIdx.x * 256 + threadIdx.x;
    if (i >= GG * CC) return;
    int g = i / CC, c = i % CC;
    float s = bc[c];
    for (int k = 0; k < 128; k++) s += pooled[g * 128 + k] * Wc[k * CC + c];
    out[i] = s;
}

// ---------------- launch ----------------

extern "C" void kernel_launch(void* const* d_in, const int* in_sizes, int n_in,
                              void* d_out, int out_size, void* d_ws, size_t ws_size,
                              hipStream_t stream) {
    const float* x = (const float*)d_in[0];
    const int* ei = (const int*)d_in[1];
    const int* batch = (const int*)d_in[2];
    const float* W1 = (const float*)d_in[3];
    const float* b1 = (const float*)d_in[4];
    const float* gamma1 = (const float*)d_in[5];
    const float* beta1 = (const float*)d_in[6];
    const float* Wl = (const float*)d_in[7];
    const float* bl = (const float*)d_in[8];
    const float* Wr = (const float*)d_in[9];
    const float* gamma2 = (const float*)d_in[10];
    const float* beta2 = (const float*)d_in[11];
    const float* W3 = (const float*)d_in[12];
    const float* att_src = (const float*)d_in[13];
    const float* att_dst = (const float*)d_in[14];
    const float* b3 = (const float*)d_in[15];
    const float* gamma3 = (const float*)d_in[16];
    const float* beta3 = (const float*)d_in[17];
    const float* Wc = (const float*)d_in[18];
    const float* bc = (const float*)d_in[19];

    char* w = (char*)d_ws;
    const size_t SZ_NH = (size_t)NN * 128 * 4;  // 25.6 MB
    float* bufA = (float*)(w + 0);
    float* bufB = (float*)(w + SZ_NH);
    float* bufC = (float*)(w + 2 * SZ_NH);
    float* aggD = (float*)(w + 3 * SZ_NH);            // N x 384
    size_t o = 3 * SZ_NH + (size_t)NN * 384 * 4;
    int* csr = (int*)(w + o); o += (size_t)EE * 4;
    int* deg = (int*)(w + o); o += (size_t)NN * 4;
    int* row_start = (int*)(w + o); o += (size_t)NN * 4;
    int* cursor = (int*)(w + o); o += (size_t)NN * 4;
    float* dinv = (float*)(w + o); o += (size_t)NN * 4;
    float* inv_sage = (float*)(w + o); o += (size_t)NN * 4;
    float* asrc = (float*)(w + o); o += (size_t)NN * 3 * 4;
    float* adst = (float*)(w + o); o += (size_t)NN * 3 * 4;
    float* bn_sums = (float*)(w + o); o += 3 * 256 * 4;
    int* blk = (int*)(w + o); o += 1024;
    float* poolacc = (float*)(w + o); o += (size_t)GG * 128 * 4;
    float* cntf = (float*)(w + o); o += (size_t)GG * 4;
    float* wsrc = (float*)(w + o); o += 384 * 4;
    float* wdst = (float*)(w + o); o += 384 * 4;
    float4* alphaE = (float4*)(w + o); o += (size_t)EE * 16;
    float4* aself = (float4*)(w + o); o += (size_t)NN * 16;
    short* w1hi = (short*)(w + o); o += (size_t)128 * 128 * 2;
    short* w1lo = (short*)(w + o); o += (size_t)128 * 128 * 2;
    short* wshi = (short*)(w + o); o += (size_t)256 * 128 * 2;
    short* wslo = (short*)(w + o); o += (size_t)256 * 128 * 2;
    short* w3hi = (short*)(w + o); o += (size_t)384 * 128 * 2;
    short* w3lo = (short*)(w + o); o += (size_t)384 * 128 * 2;

    float* outp = (float*)d_out;

    const int NB_SCAN = (NN + 255) / 256;  // 196
    const int EB = (EE + 255) / 256;
    const int NW4 = (NN + 3) / 4;           // wave-per-node kernels
    const int GB = (NN + 127) / 128;        // MFMA gemm blocks = 391

    hipMemsetAsync(deg, 0, (size_t)NN * 4, stream);
    hipMemsetAsync(bn_sums, 0, 3 * 256 * 4, stream);
    hipMemsetAsync(poolacc, 0, ((size_t)GG * 128 + GG) * 4, stream);

    k_count_deg<<<EB, 256, 0, stream>>>(ei, deg);
    k_scan1<<<NB_SCAN, 256, 0, stream>>>(deg, row_start, blk);
    k_scan2<<<1, 256, 0, stream>>>(blk, NB_SCAN);
    k_scan3<<<NB_SCAN, 256, 0, stream>>>(row_start, blk, deg, cursor, dinv, inv_sage);
    k_fill<<<EB, 256, 0, stream>>>(ei, cursor, csr);

    // Weight prep
    k_att_fold<<<1, 384, 0, stream>>>(W3, att_src, att_dst, wsrc, wdst);
    k_prep_w<<<64, 256, 0, stream>>>(W1, w1hi, w1lo, 128 * 128, 0);
    k_prep_w<<<64, 256, 0, stream>>>(Wl, wshi, wslo, 128 * 128, 0);
    k_prep_w<<<64, 256, 0, stream>>>(Wr, wshi, wslo, 128 * 128, 2);
    k_prep_w3<<<192, 256, 0, stream>>>(W3, w3hi, w3lo);

    // Layer 1: GCN
    k_gemm_mfma<<<GB, 256, 0, stream>>>(x, nullptr, w1hi, w1lo, nullptr, bufB, NN, 2, 2, 128);
    k_gcn_agg<<<NW4, 256, 0, stream>>>(bufB, row_start, deg, csr, dinv, b1, bufA);
    k_bn_stats<<<1024, 128, 0, stream>>>(bufA, bn_sums);
    k_bn_elu<<<NN * 32 / 256, 256, 0, stream>>>(bufA, bn_sums, gamma1, beta1);

    // Layer 2: SAGE (fused K=256: [agg | h1'] @ [Wl; Wr] + bl)
    k_sage_agg<<<NW4, 256, 0, stream>>>(bufA, row_start, deg, csr, inv_sage, bufB);
    k_gemm_mfma<<<GB, 256, 0, stream>>>(bufB, bufA, wshi, wslo, bl, bufC, NN, 2, 4, 128);
    k_bn_stats<<<1024, 128, 0, stream>>>(bufC, bn_sums + 256);
    k_bn_elu_att<<<NN * 32 / 256, 256, 0, stream>>>(bufC, bn_sums + 256, gamma2, beta2,
                                                    wsrc, wdst, asrc, adst);

    // Layer 3: GAT (alpha precompute -> light aggregation -> GEMM)
    k_alpha<<<NW4, 256, 0, stream>>>(row_start, deg, csr, asrc, adst, alphaE, aself);
    k_gat_agg2<<<NW4, 256, 0, stream>>>(bufC, row_start, deg, csr, alphaE, aself, aggD);
    k_gemm_mfma<<<GB, 256, 0, stream>>>(aggD, nullptr, w3hi, w3lo, b3, bufA, NN, 6, 6, 384);
    k_bn_stats<<<1024, 128, 0, stream>>>(bufA, bn_sums + 512);
    k_bn_elu<<<NN * 32 / 256, 256, 0, stream>>>(bufA, bn_sums + 512, gamma3, beta3);

    // Pool + classifier
    k_pool_partial<<<POOL_BLOCKS, 128, 0, stream>>>(bufA, batch, poolacc, cntf);
    k_pool_fin<<<GG, 128, 0, stream>>>(poolacc, cntf, outp);
    k_logits<<<(GG * CC + 255) / 256, 256, 0, stream>>>(outp, Wc, bc, outp + GG * HH);
}

// Round 6
// 558.421 us; speedup vs baseline: 1.7785x; 1.2070x over previous
//
#include <hip/hip_runtime.h>
#include <math.h>

#define NN 50000
#define EE 500000
#define HH 128
#define NHEADS 3
#define CC 10
#define GG 64
#define EPSV 1e-5f
#define SLOPE 0.2f

typedef __attribute__((ext_vector_type(8))) short short8;
typedef __attribute__((ext_vector_type(4))) float f32x4;

// ---------------- bf16 helpers (RNE to avoid systematic bias) ----------------

__device__ __forceinline__ unsigned short f2b(float x) {
    unsigned int u = __builtin_bit_cast(unsigned int, x);
    return (unsigned short)((u + 0x7fffu + ((u >> 16) & 1u)) >> 16);
}
__device__ __forceinline__ unsigned int pack2(float a, float b) {
    return (unsigned int)f2b(a) | ((unsigned int)f2b(b) << 16);
}
__device__ __forceinline__ float2 b2f2(unsigned int u) {
    float2 r;
    r.x = __builtin_bit_cast(float, u << 16);
    r.y = __builtin_bit_cast(float, u & 0xffff0000u);
    return r;
}

// ---------------- CSR build ----------------

__global__ void k_count_deg(const int* __restrict__ ei, int* __restrict__ deg) {
    int e = blockIdx.x * 256 + threadIdx.x;
    if (e < EE) atomicAdd(&deg[ei[EE + e]], 1);
}

__global__ void k_scan1(const int* __restrict__ deg, int* __restrict__ row_start,
                        int* __restrict__ blk) {
    __shared__ int s[256];
    int i = blockIdx.x * 256 + threadIdx.x;
    int v = (i < NN) ? deg[i] : 0;
    s[threadIdx.x] = v;
    __syncthreads();
    for (int o = 1; o < 256; o <<= 1) {
        int t = (threadIdx.x >= o) ? s[threadIdx.x - o] : 0;
        __syncthreads();
        s[threadIdx.x] += t;
        __syncthreads();
    }
    if (i < NN) row_start[i] = s[threadIdx.x] - v;
    if (threadIdx.x == 255) blk[blockIdx.x] = s[255];
}

__global__ void k_scan2(int* __restrict__ blk, int nb) {
    __shared__ int s[256];
    int v = (threadIdx.x < nb) ? blk[threadIdx.x] : 0;
    s[threadIdx.x] = v;
    __syncthreads();
    for (int o = 1; o < 256; o <<= 1) {
        int t = (threadIdx.x >= o) ? s[threadIdx.x - o] : 0;
        __syncthreads();
        s[threadIdx.x] += t;
        __syncthreads();
    }
    if (threadIdx.x < nb) blk[threadIdx.x] = s[threadIdx.x] - v;
}

__global__ void k_scan3(int* __restrict__ row_start, const int* __restrict__ blk,
                        const int* __restrict__ deg, int* __restrict__ cursor,
                        float* __restrict__ dinv, float* __restrict__ inv_sage) {
    int i = blockIdx.x * 256 + threadIdx.x;
    if (i < NN) {
        int rs = row_start[i] + blk[blockIdx.x];
        row_start[i] = rs;
        cursor[i] = rs;
        int d = deg[i];
        dinv[i] = rsqrtf((float)(d + 1));
        inv_sage[i] = 1.0f / (float)(d > 1 ? d : 1);
    }
}

__global__ void k_fill(const int* __restrict__ ei, int* __restrict__ cursor,
                       int* __restrict__ csr_src) {
    int e = blockIdx.x * 256 + threadIdx.x;
    if (e < EE) {
        int d = ei[EE + e];
        int p = atomicAdd(&cursor[d], 1);
        csr_src[p] = ei[e];
    }
}

// ---------------- Weight prep: fp32 -> fragment-ordered bf16 hi/lo ----------------

__device__ __forceinline__ void split_store(float x, size_t dst, short* hi, short* lo) {
    unsigned int ux = __builtin_bit_cast(unsigned int, x);
    unsigned short hx = (unsigned short)(ux >> 16);
    float fx = __builtin_bit_cast(float, ux & 0xffff0000u);
    unsigned short lx = (unsigned short)(__builtin_bit_cast(unsigned int, x - fx) >> 16);
    hi[dst] = (short)hx;
    lo[dst] = (short)lx;
}

__global__ void k_prep_w(const float* __restrict__ W, short* __restrict__ hi,
                         short* __restrict__ lo, int kelems, int cBase) {
    int i = blockIdx.x * 256 + threadIdx.x;
    if (i >= kelems) return;
    int k = i >> 7, n = i & 127;
    int c = (k >> 6) + cBase;
    int s = (k >> 5) & 1, quad = (k >> 3) & 3, j = k & 7;
    int G = n >> 4, l = quad * 16 + (n & 15);
    size_t dst = ((((size_t)(c * 2 + s)) * 8 + G) * 64 + l) * 8 + j;
    split_store(W[i], dst, hi, lo);
}

__global__ void k_prep_w3(const float* __restrict__ W3, short* __restrict__ hi,
                          short* __restrict__ lo) {
    int i = blockIdx.x * 256 + threadIdx.x;
    if (i >= 384 * 128) return;
    int k = i >> 7, n = i & 127;
    int h = k >> 7, kk = k & 127;
    float x = W3[(size_t)kk * 384 + h * 128 + n] * (1.f / 3.f);
    int c = k >> 6, s = (k >> 5) & 1, quad = (k >> 3) & 3, j = k & 7;
    int G = n >> 4, l = quad * 16 + (n & 15);
    size_t dst = ((((size_t)(c * 2 + s)) * 8 + G) * 64 + l) * 8 + j;
    split_store(x, dst, hi, lo);
}

// ---------------- MFMA GEMM  C = [A1|A2] @ B + bias ----------------
// ABF16: A operand already bf16 (2 MFMAs/tile); else fp32 split (3 MFMAs/tile).
// OUTB: write bf16 output; else fp32.

template <bool ABF16, bool OUTB>
__global__ __launch_bounds__(256) void k_gemm_mfma(
    const void* __restrict__ A1v, const void* __restrict__ A2v,
    const short* __restrict__ Bhi, const short* __restrict__ Blo,
    const float* __restrict__ bias, void* __restrict__ Cv,
    int M, int kc1, int kcT, int strideA1) {
    __shared__ short Ahi[128 * 72];
    __shared__ short Alo[ABF16 ? 8 : 128 * 72];
    int tid = threadIdx.x;
    int rBase = blockIdx.x * 128;
    int wv = tid >> 6, lane = tid & 63;
    int rowHalf = wv >> 1, colHalf = wv & 1;
    int quad = lane >> 4, l15 = lane & 15;

    f32x4 acc[4][4];
#pragma unroll
    for (int a = 0; a < 4; a++)
#pragma unroll
        for (int b = 0; b < 4; b++) acc[a][b] = (f32x4)(0.f);

    for (int c = 0; c < kcT; c++) {
        const void* Asrc;
        int kOff, strideA;
        if (c < kc1) { Asrc = A1v; kOff = c * 64; strideA = strideA1; }
        else { Asrc = A2v; kOff = (c - kc1) * 64; strideA = 128; }

        __syncthreads();
        if (ABF16) {
            const unsigned short* As = (const unsigned short*)Asrc;
#pragma unroll
            for (int q = 0; q < 4; q++) {
                int slot = q * 256 + tid;
                int r = slot >> 3, k8 = slot & 7;
                uint4 v = make_uint4(0, 0, 0, 0);
                int gr = rBase + r;
                if (gr < M) v = *(const uint4*)(As + (size_t)gr * strideA + kOff + k8 * 8);
                *(uint4*)(Ahi + r * 72 + k8 * 8) = v;
            }
        } else {
            const float* As = (const float*)Asrc;
#pragma unroll
            for (int q8 = 0; q8 < 8; q8++) {
                int slot = q8 * 256 + tid;
                int r = slot >> 4, k4 = slot & 15;
                float4 v = make_float4(0.f, 0.f, 0.f, 0.f);
                int gr = rBase + r;
                if (gr < M) v = *(const float4*)(As + (size_t)gr * strideA + kOff + k4 * 4);
                unsigned int ux = __builtin_bit_cast(unsigned int, v.x);
                unsigned int uy = __builtin_bit_cast(unsigned int, v.y);
                unsigned int uz = __builtin_bit_cast(unsigned int, v.z);
                unsigned int uw = __builtin_bit_cast(unsigned int, v.w);
                unsigned int hx = ux >> 16, hy = uy >> 16, hz = uz >> 16, hw = uw >> 16;
                float fx = __builtin_bit_cast(float, ux & 0xffff0000u);
                float fy = __builtin_bit_cast(float, uy & 0xffff0000u);
                float fz = __builtin_bit_cast(float, uz & 0xffff0000u);
                float fw = __builtin_bit_cast(float, uw & 0xffff0000u);
                unsigned int lx = __builtin_bit_cast(unsigned int, v.x - fx) >> 16;
                unsigned int ly = __builtin_bit_cast(unsigned int, v.y - fy) >> 16;
                unsigned int lz = __builtin_bit_cast(unsigned int, v.z - fz) >> 16;
                unsigned int lw = __builtin_bit_cast(unsigned int, v.w - fw) >> 16;
                uint2 ph = make_uint2(hx | (hy << 16), hz | (hw << 16));
                uint2 pl = make_uint2(lx | (ly << 16), lz | (lw << 16));
                *(uint2*)(Ahi + r * 72 + k4 * 4) = ph;
                *(uint2*)(Alo + r * 72 + k4 * 4) = pl;
            }
        }
        __syncthreads();

#pragma unroll
        for (int s = 0; s < 2; s++) {
            short8 ah[4], al[4];
#pragma unroll
            for (int rb = 0; rb < 4; rb++) {
                int m = rowHalf * 64 + rb * 16 + l15;
                ah[rb] = *(const short8*)(Ahi + m * 72 + s * 32 + quad * 8);
                if (!ABF16) al[rb] = *(const short8*)(Alo + m * 72 + s * 32 + quad * 8);
            }
#pragma unroll
            for (int cg = 0; cg < 4; cg++) {
                int G = colHalf * 4 + cg;
                size_t bo = ((((size_t)(c * 2 + s)) * 8 + G) * 64 + lane) * 8;
                short8 bh = *(const short8*)(Bhi + bo);
                short8 bl = *(const short8*)(Blo + bo);
#pragma unroll
                for (int rb = 0; rb < 4; rb++) {
                    acc[rb][cg] = __builtin_amdgcn_mfma_f32_16x16x32_bf16(ah[rb], bh, acc[rb][cg], 0, 0, 0);
                    if (!ABF16)
                        acc[rb][cg] = __builtin_amdgcn_mfma_f32_16x16x32_bf16(al[rb], bh, acc[rb][cg], 0, 0, 0);
                    acc[rb][cg] = __builtin_amdgcn_mfma_f32_16x16x32_bf16(ah[rb], bl, acc[rb][cg], 0, 0, 0);
                }
            }
        }
    }

#pragma unroll
    for (int cg = 0; cg < 4; cg++) {
        int col = colHalf * 64 + cg * 16 + l15;
        float bv = bias ? bias[col] : 0.f;
#pragma unroll
        for (int rb = 0; rb < 4; rb++) {
#pragma unroll
            for (int r = 0; r < 4; r++) {
                int row = rBase + rowHalf * 64 + rb * 16 + quad * 4 + r;
                if (row < M) {
                    float ov = acc[rb][cg][r] + bv;
                    if (OUTB) ((unsigned short*)Cv)[(size_t)row * HH + col] = f2b(ov);
                    else ((float*)Cv)[(size_t)row * HH + col] = ov;
                }
            }
        }
    }
}

// ---------------- Aggregations (1 wave per node, bf16 gathers, 4x unroll) -------

__global__ void k_gcn_agg(const unsigned int* __restrict__ hb, const int* __restrict__ row_start,
                          const int* __restrict__ deg, const int* __restrict__ csr,
                          const float* __restrict__ dinv, const float* __restrict__ b1,
                          float* __restrict__ out) {
    int n = blockIdx.x * 4 + (threadIdx.x >> 6);
    if (n >= NN) return;
    int lane = threadIdx.x & 63;
    float di = dinv[n];
    float2 hv = b2f2(hb[(size_t)n * 64 + lane]);
    float ws = di * di;
    float2 acc = make_float2(hv.x * ws, hv.y * ws);
    int s0 = row_start[n], cnt = deg[n];
    int i = 0;
    for (; i + 4 <= cnt; i += 4) {
        int ss[4]; float ww[4]; unsigned int vv[4];
#pragma unroll
        for (int j = 0; j < 4; j++) ss[j] = csr[s0 + i + j];
#pragma unroll
        for (int j = 0; j < 4; j++) { ww[j] = dinv[ss[j]]; vv[j] = hb[(size_t)ss[j] * 64 + lane]; }
#pragma unroll
        for (int j = 0; j < 4; j++) {
            float2 v = b2f2(vv[j]);
            float wj = ww[j] * di;
            acc.x += v.x * wj; acc.y += v.y * wj;
        }
    }
    for (; i < cnt; i++) {
        int s = csr[s0 + i];
        float wj = dinv[s] * di;
        float2 v = b2f2(hb[(size_t)s * 64 + lane]);
        acc.x += v.x * wj; acc.y += v.y * wj;
    }
    float2 bb = ((const float2*)b1)[lane];
    ((float2*)out)[(size_t)n * 64 + lane] = make_float2(acc.x + bb.x, acc.y + bb.y);
}

__global__ void k_sage_agg(const unsigned int* __restrict__ hb, const int* __restrict__ row_start,
                           const int* __restrict__ deg, const int* __restrict__ csr,
                           const float* __restrict__ inv_sage, unsigned int* __restrict__ outb) {
    int n = blockIdx.x * 4 + (threadIdx.x >> 6);
    if (n >= NN) return;
    int lane = threadIdx.x & 63;
    float2 acc = make_float2(0.f, 0.f);
    int s0 = row_start[n], cnt = deg[n];
    int i = 0;
    for (; i + 4 <= cnt; i += 4) {
        int ss[4]; unsigned int vv[4];
#pragma unroll
        for (int j = 0; j < 4; j++) ss[j] = csr[s0 + i + j];
#pragma unroll
        for (int j = 0; j < 4; j++) vv[j] = hb[(size_t)ss[j] * 64 + lane];
#pragma unroll
        for (int j = 0; j < 4; j++) {
            float2 v = b2f2(vv[j]);
            acc.x += v.x; acc.y += v.y;
        }
    }
    for (; i < cnt; i++) {
        float2 v = b2f2(hb[(size_t)csr[s0 + i] * 64 + lane]);
        acc.x += v.x; acc.y += v.y;
    }
    float sc = inv_sage[n];
    outb[(size_t)n * 64 + lane] = pack2(acc.x * sc, acc.y * sc);
}

// ---- GAT precomputes ----

__global__ void k_att_fold(const float* __restrict__ W3, const float* __restrict__ att_src,
                           const float* __restrict__ att_dst, float* __restrict__ wsrc,
                           float* __restrict__ wdst) {
    int tid = threadIdx.x;  // 384
    int h = tid >> 7, k = tid & 127;
    float s1 = 0.f, s2 = 0.f;
    const float* wrow = W3 + (size_t)k * 384 + h * 128;
    const float* as = att_src + h * 128;
    const float* ad = att_dst + h * 128;
    for (int j = 0; j < 128; j++) {
        float wv = wrow[j];
        s1 += wv * as[j];
        s2 += wv * ad[j];
    }
    wsrc[tid] = s1;
    wdst[tid] = s2;
}

__device__ __forceinline__ float lrelu(float a) { return fmaxf(a, SLOPE * a); }

__global__ void k_alpha(const int* __restrict__ row_start, const int* __restrict__ deg,
                        const int* __restrict__ csr, const float4* __restrict__ asrc4,
                        const float4* __restrict__ adst4, float4* __restrict__ alphaE,
                        float4* __restrict__ aself) {
    int n = blockIdx.x * 4 + (threadIdx.x >> 6);
    if (n >= NN) return;
    int lane = threadIdx.x & 63;
    float4 ad = adst4[n];
    float4 asv = asrc4[n];
    float es0 = lrelu(asv.x + ad.x), es1 = lrelu(asv.y + ad.y), es2 = lrelu(asv.z + ad.z);
    int s0 = row_start[n], cnt = deg[n];
    if (cnt <= 64) {
        // fast path: everything in registers, single pass
        bool valid = lane < cnt;
        float e0 = -3e38f, e1 = -3e38f, e2 = -3e38f;
        if (valid) {
            int s = csr[s0 + lane];
            float4 a4 = asrc4[s];
            e0 = lrelu(a4.x + ad.x); e1 = lrelu(a4.y + ad.y); e2 = lrelu(a4.z + ad.z);
        }
        float M0 = e0, M1 = e1, M2 = e2;
#pragma unroll
        for (int o = 32; o > 0; o >>= 1) {
            M0 = fmaxf(M0, __shfl_xor(M0, o, 64));
            M1 = fmaxf(M1, __shfl_xor(M1, o, 64));
            M2 = fmaxf(M2, __shfl_xor(M2, o, 64));
        }
        float m0 = fmaxf(es0, M0), m1 = fmaxf(es1, M1), m2 = fmaxf(es2, M2);
        float w0 = valid ? __expf(e0 - m0) : 0.f;
        float w1 = valid ? __expf(e1 - m1) : 0.f;
        float w2 = valid ? __expf(e2 - m2) : 0.f;
        float S0 = w0, S1 = w1, S2 = w2;
#pragma unroll
        for (int o = 32; o > 0; o >>= 1) {
            S0 += __shfl_xor(S0, o, 64);
            S1 += __shfl_xor(S1, o, 64);
            S2 += __shfl_xor(S2, o, 64);
        }
        float sw0 = __expf(es0 - m0), sw1 = __expf(es1 - m1), sw2 = __expf(es2 - m2);
        float r0 = 1.f / (S0 + sw0), r1 = 1.f / (S1 + sw1), r2 = 1.f / (S2 + sw2);
        if (valid) alphaE[s0 + lane] = make_float4(w0 * r0, w1 * r1, w2 * r2, 0.f);
        if (lane == 0) aself[n] = make_float4(sw0 * r0, sw1 * r1, sw2 * r2, 0.f);
    } else {
        float m0 = es0, m1 = es1, m2 = es2;
        for (int base = 0; base < cnt; base += 64) {
            int i2 = base + lane;
            float e0 = -3e38f, e1 = -3e38f, e2 = -3e38f;
            if (i2 < cnt) {
                int s = csr[s0 + i2];
                float4 a4 = asrc4[s];
                e0 = lrelu(a4.x + ad.x); e1 = lrelu(a4.y + ad.y); e2 = lrelu(a4.z + ad.z);
                alphaE[s0 + i2] = make_float4(e0, e1, e2, 0.f);
            }
#pragma unroll
            for (int o = 32; o > 0; o >>= 1) {
                e0 = fmaxf(e0, __shfl_xor(e0, o, 64));
                e1 = fmaxf(e1, __shfl_xor(e1, o, 64));
                e2 = fmaxf(e2, __shfl_xor(e2, o, 64));
            }
            m0 = fmaxf(m0, e0); m1 = fmaxf(m1, e1); m2 = fmaxf(m2, e2);
        }
        float l0 = __expf(es0 - m0), l1 = __expf(es1 - m1), l2 = __expf(es2 - m2);
        for (int base = 0; base < cnt; base += 64) {
            int i2 = base + lane;
            float w0 = 0.f, w1 = 0.f, w2 = 0.f;
            if (i2 < cnt) {
                float4 e = alphaE[s0 + i2];
                w0 = __expf(e.x - m0); w1 = __expf(e.y - m1); w2 = __expf(e.z - m2);
            }
#pragma unroll
            for (int o = 32; o > 0; o >>= 1) {
                w0 += __shfl_xor(w0, o, 64);
                w1 += __shfl_xor(w1, o, 64);
                w2 += __shfl_xor(w2, o, 64);
            }
            l0 += w0; l1 += w1; l2 += w2;
        }
        float r0 = 1.f / l0, r1 = 1.f / l1, r2 = 1.f / l2;
        if (lane == 0)
            aself[n] = make_float4(__expf(es0 - m0) * r0, __expf(es1 - m1) * r1,
                                   __expf(es2 - m2) * r2, 0.f);
        for (int base = 0; base < cnt; base += 64) {
            int i2 = base + lane;
            if (i2 < cnt) {
                float4 e = alphaE[s0 + i2];
                alphaE[s0 + i2] = make_float4(__expf(e.x - m0) * r0, __expf(e.y - m1) * r1,
                                              __expf(e.z - m2) * r2, 0.f);
            }
        }
    }
}

__global__ void k_gat_agg2(const unsigned int* __restrict__ hb, const int* __restrict__ row_start,
                           const int* __restrict__ deg, const int* __restrict__ csr,
                           const float4* __restrict__ alphaE, const float4* __restrict__ aself,
                           unsigned int* __restrict__ aggb) {
    int n = blockIdx.x * 4 + (threadIdx.x >> 6);
    if (n >= NN) return;
    int lane = threadIdx.x & 63;
    float4 asf = aself[n];
    float2 hv = b2f2(hb[(size_t)n * 64 + lane]);
    float2 a0 = make_float2(hv.x * asf.x, hv.y * asf.x);
    float2 a1 = make_float2(hv.x * asf.y, hv.y * asf.y);
    float2 a2 = make_float2(hv.x * asf.z, hv.y * asf.z);
    int s0 = row_start[n], cnt = deg[n];
    int i = 0;
    for (; i + 4 <= cnt; i += 4) {
        int ss[4]; float4 al[4]; unsigned int vv[4];
#pragma unroll
        for (int j = 0; j < 4; j++) ss[j] = csr[s0 + i + j];
#pragma unroll
        for (int j = 0; j < 4; j++) { al[j] = alphaE[s0 + i + j]; vv[j] = hb[(size_t)ss[j] * 64 + lane]; }
#pragma unroll
        for (int j = 0; j < 4; j++) {
            float2 v = b2f2(vv[j]);
            a0.x += al[j].x * v.x; a0.y += al[j].x * v.y;
            a1.x += al[j].y * v.x; a1.y += al[j].y * v.y;
            a2.x += al[j].z * v.x; a2.y += al[j].z * v.y;
        }
    }
    for (; i < cnt; i++) {
        int s = csr[s0 + i];
        float4 al = alphaE[s0 + i];
        float2 v = b2f2(hb[(size_t)s * 64 + lane]);
        a0.x += al.x * v.x; a0.y += al.x * v.y;
        a1.x += al.y * v.x; a1.y += al.y * v.y;
        a2.x += al.z * v.x; a2.y += al.z * v.y;
    }
    unsigned int* op = aggb + (size_t)n * 192;
    op[lane] = pack2(a0.x, a0.y);
    op[64 + lane] = pack2(a1.x, a1.y);
    op[128 + lane] = pack2(a2.x, a2.y);
}

// ---------------- BatchNorm + ELU ----------------

__global__ void k_bn_stats(const float* __restrict__ h, float* __restrict__ sums) {
    int f = threadIdx.x;  // 128
    int rows_per = (NN + gridDim.x - 1) / gridDim.x;
    int r0 = blockIdx.x * rows_per;
    int r1 = r0 + rows_per;
    if (r1 > NN) r1 = NN;
    float s = 0.f, sq = 0.f;
    for (int r = r0; r < r1; r++) {
        float v = h[(size_t)r * 128 + f];
        s += v;
        sq += v * v;
    }
    atomicAdd(&sums[f], s);
    atomicAdd(&sums[128 + f], sq);
}

__device__ __forceinline__ float elu1(float x) { return x > 0.f ? x : (__expf(x) - 1.f); }

__device__ __forceinline__ float4 bn_apply4(float4 v, const float* sums,
                                            const float* gamma, const float* beta, int f4) {
    const float invN = 1.0f / NN;
    float4 s4 = *(const float4*)(sums + f4);
    float4 q4 = *(const float4*)(sums + 128 + f4);
    float4 g4 = *(const float4*)(gamma + f4);
    float4 b4 = *(const float4*)(beta + f4);
    float mx = s4.x * invN, my = s4.y * invN, mz = s4.z * invN, mw = s4.w * invN;
    float scx = rsqrtf(q4.x * invN - mx * mx + EPSV) * g4.x;
    float scy = rsqrtf(q4.y * invN - my * my + EPSV) * g4.y;
    float scz = rsqrtf(q4.z * invN - mz * mz + EPSV) * g4.z;
    float scw = rsqrtf(q4.w * invN - mw * mw + EPSV) * g4.w;
    v.x = elu1(v.x * scx + (b4.x - mx * scx));
    v.y = elu1(v.y * scy + (b4.y - my * scy));
    v.z = elu1(v.z * scz + (b4.z - mz * scz));
    v.w = elu1(v.w * scw + (b4.w - mw * scw));
    return v;
}

// hb (optional): bf16 copy for gather/GEMM-A consumers
__global__ void k_bn_elu(float* __restrict__ h, const float* __restrict__ sums,
                         const float* __restrict__ gamma, const float* __restrict__ beta,
                         unsigned int* __restrict__ hb) {
    int i = blockIdx.x * 256 + threadIdx.x;  // NN*32
    int f4 = (i & 31) << 2;
    float4 v = bn_apply4(((float4*)h)[i], sums, gamma, beta, f4);
    ((float4*)h)[i] = v;
    if (hb) {
        uint2 p = make_uint2(pack2(v.x, v.y), pack2(v.z, v.w));
        *(uint2*)(hb + ((size_t)(i >> 5)) * 64 + (i & 31) * 2) = p;
    }
}

// layer-2 variant: bf16 copy + attention logits into padded float4 arrays
__global__ void k_bn_elu_att(float* __restrict__ h, const float* __restrict__ sums,
                             const float* __restrict__ gamma, const float* __restrict__ beta,
                             const float* __restrict__ wsrc, const float* __restrict__ wdst,
                             unsigned int* __restrict__ hb, float4* __restrict__ asrc4,
                             float4* __restrict__ adst4) {
    int i = blockIdx.x * 256 + threadIdx.x;
    int fi = i & 31;
    int f4 = fi << 2;
    float4 v = bn_apply4(((float4*)h)[i], sums, gamma, beta, f4);
    ((float4*)h)[i] = v;
    uint2 p = make_uint2(pack2(v.x, v.y), pack2(v.z, v.w));
    *(uint2*)(hb + ((size_t)(i >> 5)) * 64 + fi * 2) = p;
    const float4* ws4 = (const float4*)wsrc;
    const float4* wd4 = (const float4*)wdst;
    float d[6];
#pragma unroll
    for (int hd = 0; hd < 3; hd++) {
        float4 a = ws4[hd * 32 + fi];
        float4 b = wd4[hd * 32 + fi];
        d[hd] = v.x * a.x + v.y * a.y + v.z * a.z + v.w * a.w;
        d[3 + hd] = v.x * b.x + v.y * b.y + v.z * b.z + v.w * b.w;
    }
#pragma unroll
    for (int o = 16; o > 0; o >>= 1) {
#pragma unroll
        for (int j = 0; j < 6; j++) d[j] += __shfl_xor(d[j], o, 64);
    }
    if ((threadIdx.x & 31) == 0) {
        int r = i >> 5;
        asrc4[r] = make_float4(d[0], d[1], d[2], 0.f);
        adst4[r] = make_float4(d[3], d[4], d[5], 0.f);
    }
}

// ---------------- Pool + classifier ----------------

#define POOL_BLOCKS 800

__global__ void k_pool_partial(const float* __restrict__ h, const int* __restrict__ batch,
                               float* __restrict__ pool, float* __restrict__ cntf) {
    const int RP = (NN + POOL_BLOCKS - 1) / POOL_BLOCKS;
    int r0 = blockIdx.x * RP;
    int r1 = r0 + RP;
    if (r1 > NN) r1 = NN;
    if (r0 >= r1) return;
    int f = threadIdx.x;
    int g = batch[r0];
    float s = 0.f, c = 0.f;
    for (int r = r0; r < r1; r++) {
        int gr = batch[r];
        if (gr != g) {
            atomicAdd(&pool[g * 128 + f], s);
            if (f == 0) atomicAdd(&cntf[g], c);
            s = 0.f; c = 0.f; g = gr;
        }
        s += h[(size_t)r * 128 + f];
        c += 1.f;
    }
    atomicAdd(&pool[g * 128 + f], s);
    if (f == 0) atomicAdd(&cntf[g], c);
}

__global__ void k_pool_fin(const float* __restrict__ pool, const float* __restrict__ cntf,
                           float* __restrict__ out) {
    int g = blockIdx.x;
    int f = threadIdx.x;
    float c = cntf[g];
    out[g * 128 + f] = pool[g * 128 + f] / fmaxf(c, 1.f);
}

__global__ void k_logits(const float* __restrict__ pooled, const float* __restrict__ Wc,
                         const float* __restrict__ bc, float* __restrict__ out) {
    int i = blockIdx.x * 256 + threadIdx.x;
    if (i >= GG * CC) return;
    int g = i / CC, c = i % CC;
    float s = bc[c];
    for (int k = 0; k < 128; k++) s += pooled[g * 128 + k] * Wc[k * CC + c];
    out[i] = s;
}

// ---------------- launch ----------------

extern "C" void kernel_launch(void* const* d_in, const int* in_sizes, int n_in,
                              void* d_out, int out_size, void* d_ws, size_t ws_size,
                              hipStream_t stream) {
    const float* x = (const float*)d_in[0];
    const int* ei = (const int*)d_in[1];
    const int* batch = (const int*)d_in[2];
    const float* W1 = (const float*)d_in[3];
    const float* b1 = (const float*)d_in[4];
    const float* gamma1 = (const float*)d_in[5];
    const float* beta1 = (const float*)d_in[6];
    const float* Wl = (const float*)d_in[7];
    const float* bl = (const float*)d_in[8];
    const float* Wr = (const float*)d_in[9];
    const float* gamma2 = (const float*)d_in[10];
    const float* beta2 = (const float*)d_in[11];
    const float* W3 = (const float*)d_in[12];
    const float* att_src = (const float*)d_in[13];
    const float* att_dst = (const float*)d_in[14];
    const float* b3 = (const float*)d_in[15];
    const float* gamma3 = (const float*)d_in[16];
    const float* beta3 = (const float*)d_in[17];
    const float* Wc = (const float*)d_in[18];
    const float* bc = (const float*)d_in[19];

    char* w = (char*)d_ws;
    size_t o = 0;
    float* bufA = (float*)(w + o); o += (size_t)NN * 128 * 4;   // fp32 h (layer1 out / layer3 out)
    float* bufC = (float*)(w + o); o += (size_t)NN * 128 * 4;   // fp32 h2
    unsigned int* h0b = (unsigned int*)(w + o); o += (size_t)NN * 128 * 2;   // gemm1 out bf16
    unsigned int* h1b = (unsigned int*)(w + o); o += (size_t)NN * 128 * 2;   // h1 post-BN bf16
    unsigned int* sageb = (unsigned int*)(w + o); o += (size_t)NN * 128 * 2; // sage agg bf16
    unsigned int* h2b = (unsigned int*)(w + o); o += (size_t)NN * 128 * 2;   // h2 post-BN bf16
    unsigned int* aggDb = (unsigned int*)(w + o); o += (size_t)NN * 384 * 2; // gat agg bf16
    int* csr = (int*)(w + o); o += (size_t)EE * 4;
    int* deg = (int*)(w + o); o += (size_t)NN * 4;
    int* row_start = (int*)(w + o); o += (size_t)NN * 4;
    int* cursor = (int*)(w + o); o += (size_t)NN * 4;
    float* dinv = (float*)(w + o); o += (size_t)NN * 4;
    float* inv_sage = (float*)(w + o); o += (size_t)NN * 4;
    float4* asrc4 = (float4*)(w + o); o += (size_t)NN * 16;
    float4* adst4 = (float4*)(w + o); o += (size_t)NN * 16;
    float* bn_sums = (float*)(w + o); o += 3 * 256 * 4;
    int* blk = (int*)(w + o); o += 1024;
    float* poolacc = (float*)(w + o); o += (size_t)GG * 128 * 4;
    float* cntf = (float*)(w + o); o += (size_t)GG * 4;
    float* wsrc = (float*)(w + o); o += 384 * 4;
    float* wdst = (float*)(w + o); o += 384 * 4;
    float4* alphaE = (float4*)(w + o); o += (size_t)EE * 16;
    float4* aself = (float4*)(w + o); o += (size_t)NN * 16;
    short* w1hi = (short*)(w + o); o += (size_t)128 * 128 * 2;
    short* w1lo = (short*)(w + o); o += (size_t)128 * 128 * 2;
    short* wshi = (short*)(w + o); o += (size_t)256 * 128 * 2;
    short* wslo = (short*)(w + o); o += (size_t)256 * 128 * 2;
    short* w3hi = (short*)(w + o); o += (size_t)384 * 128 * 2;
    short* w3lo = (short*)(w + o); o += (size_t)384 * 128 * 2;

    float* outp = (float*)d_out;

    const int NB_SCAN = (NN + 255) / 256;
    const int EB = (EE + 255) / 256;
    const int NW4 = (NN + 3) / 4;
    const int GB = (NN + 127) / 128;

    hipMemsetAsync(deg, 0, (size_t)NN * 4, stream);
    hipMemsetAsync(bn_sums, 0, 3 * 256 * 4, stream);
    hipMemsetAsync(poolacc, 0, ((size_t)GG * 128 + GG) * 4, stream);

    k_count_deg<<<EB, 256, 0, stream>>>(ei, deg);
    k_scan1<<<NB_SCAN, 256, 0, stream>>>(deg, row_start, blk);
    k_scan2<<<1, 256, 0, stream>>>(blk, NB_SCAN);
    k_scan3<<<NB_SCAN, 256, 0, stream>>>(row_start, blk, deg, cursor, dinv, inv_sage);
    k_fill<<<EB, 256, 0, stream>>>(ei, cursor, csr);

    // Weight prep
    k_att_fold<<<1, 384, 0, stream>>>(W3, att_src, att_dst, wsrc, wdst);
    k_prep_w<<<64, 256, 0, stream>>>(W1, w1hi, w1lo, 128 * 128, 0);
    k_prep_w<<<64, 256, 0, stream>>>(Wl, wshi, wslo, 128 * 128, 0);
    k_prep_w<<<64, 256, 0, stream>>>(Wr, wshi, wslo, 128 * 128, 2);
    k_prep_w3<<<192, 256, 0, stream>>>(W3, w3hi, w3lo);

    // Layer 1: GCN (GEMM1 writes bf16 only; agg gathers bf16)
    k_gemm_mfma<false, true><<<GB, 256, 0, stream>>>(x, nullptr, w1hi, w1lo, nullptr, h0b,
                                                     NN, 2, 2, 128);
    k_gcn_agg<<<NW4, 256, 0, stream>>>(h0b, row_start, deg, csr, dinv, b1, bufA);
    k_bn_stats<<<1024, 128, 0, stream>>>(bufA, bn_sums);
    k_bn_elu<<<NN * 32 / 256, 256, 0, stream>>>(bufA, bn_sums, gamma1, beta1, h1b);

    // Layer 2: SAGE (fused K=256 bf16-A GEMM: [sage_agg | h1] @ [Wl; Wr] + bl)
    k_sage_agg<<<NW4, 256, 0, stream>>>(h1b, row_start, deg, csr, inv_sage, sageb);
    k_gemm_mfma<true, false><<<GB, 256, 0, stream>>>(sageb, h1b, wshi, wslo, bl, bufC,
                                                     NN, 2, 4, 128);
    k_bn_stats<<<1024, 128, 0, stream>>>(bufC, bn_sums + 256);
    k_bn_elu_att<<<NN * 32 / 256, 256, 0, stream>>>(bufC, bn_sums + 256, gamma2, beta2,
                                                    wsrc, wdst, h2b, asrc4, adst4);

    // Layer 3: GAT
    k_alpha<<<NW4, 256, 0, stream>>>(row_start, deg, csr, asrc4, adst4, alphaE, aself);
    k_gat_agg2<<<NW4, 256, 0, stream>>>(h2b, row_start, deg, csr, alphaE, aself, aggDb);
    k_gemm_mfma<true, false><<<GB, 256, 0, stream>>>(aggDb, nullptr, w3hi, w3lo, b3, bufA,
                                                     NN, 6, 6, 384);
    k_bn_stats<<<1024, 128, 0, stream>>>(bufA, bn_sums + 512);
    k_bn_elu<<<NN * 32 / 256, 256, 0, stream>>>(bufA, bn_sums + 512, gamma3, beta3, nullptr);

    // Pool + classifier
    k_pool_partial<<<POOL_BLOCKS, 128, 0, stream>>>(bufA, batch, poolacc, cntf);
    k_pool_fin<<<GG, 128, 0, stream>>>(poolacc, cntf, outp);
    k_logits<<<(GG * CC + 255) / 256, 256, 0, stream>>>(outp, Wc, bc, outp + GG * HH);
}

// Round 7
// 455.779 us; speedup vs baseline: 2.1790x; 1.2252x over previous
//
#include <hip/hip_runtime.h>
#include <math.h>

#define NN 50000
#define EE 500000
#define HH 128
#define NHEADS 3
#define CC 10
#define GG 64
#define EPSV 1e-5f
#define SLOPE 0.2f

typedef __attribute__((ext_vector_type(8))) short short8;
typedef __attribute__((ext_vector_type(4))) float f32x4;

// ---------------- bf16 helpers (RNE) ----------------

__device__ __forceinline__ unsigned short f2b(float x) {
    unsigned int u = __builtin_bit_cast(unsigned int, x);
    return (unsigned short)((u + 0x7fffu + ((u >> 16) & 1u)) >> 16);
}
__device__ __forceinline__ unsigned int pack2(float a, float b) {
    return (unsigned int)f2b(a) | ((unsigned int)f2b(b) << 16);
}
__device__ __forceinline__ float2 b2f2(unsigned int u) {
    float2 r;
    r.x = __builtin_bit_cast(float, u << 16);
    r.y = __builtin_bit_cast(float, u & 0xffff0000u);
    return r;
}

// ---------------- fused zero-init ----------------

__global__ void k_zero(int* __restrict__ deg, float* __restrict__ bn_sums,
                       float* __restrict__ poolacc) {
    int i = blockIdx.x * 256 + threadIdx.x;
    if (i < NN) deg[i] = 0;
    if (i < 768) bn_sums[i] = 0.f;
    if (i < GG * 128 + GG) poolacc[i] = 0.f;
}

// ---------------- CSR build ----------------

__global__ void k_count_deg(const int* __restrict__ ei, int* __restrict__ deg) {
    int e = blockIdx.x * 256 + threadIdx.x;
    if (e < EE) atomicAdd(&deg[ei[EE + e]], 1);
}

__global__ void k_scan1(const int* __restrict__ deg, int* __restrict__ row_start,
                        int* __restrict__ blk) {
    __shared__ int s[256];
    int i = blockIdx.x * 256 + threadIdx.x;
    int v = (i < NN) ? deg[i] : 0;
    s[threadIdx.x] = v;
    __syncthreads();
    for (int o = 1; o < 256; o <<= 1) {
        int t = (threadIdx.x >= o) ? s[threadIdx.x - o] : 0;
        __syncthreads();
        s[threadIdx.x] += t;
        __syncthreads();
    }
    if (i < NN) row_start[i] = s[threadIdx.x] - v;
    if (threadIdx.x == 255) blk[blockIdx.x] = s[255];
}

__global__ void k_scan2(int* __restrict__ blk, int nb) {
    __shared__ int s[256];
    int v = (threadIdx.x < nb) ? blk[threadIdx.x] : 0;
    s[threadIdx.x] = v;
    __syncthreads();
    for (int o = 1; o < 256; o <<= 1) {
        int t = (threadIdx.x >= o) ? s[threadIdx.x - o] : 0;
        __syncthreads();
        s[threadIdx.x] += t;
        __syncthreads();
    }
    if (threadIdx.x < nb) blk[threadIdx.x] = s[threadIdx.x] - v;
}

__global__ void k_scan3(int* __restrict__ row_start, const int* __restrict__ blk,
                        const int* __restrict__ deg, int* __restrict__ cursor,
                        float* __restrict__ dinv, float* __restrict__ inv_sage) {
    int i = blockIdx.x * 256 + threadIdx.x;
    if (i < NN) {
        int rs = row_start[i] + blk[blockIdx.x];
        row_start[i] = rs;
        cursor[i] = rs;
        int d = deg[i];
        dinv[i] = rsqrtf((float)(d + 1));
        inv_sage[i] = 1.0f / (float)(d > 1 ? d : 1);
    }
}

__global__ void k_fill(const int* __restrict__ ei, int* __restrict__ cursor,
                       int* __restrict__ csr_src) {
    int e = blockIdx.x * 256 + threadIdx.x;
    if (e < EE) {
        int d = ei[EE + e];
        int p = atomicAdd(&cursor[d], 1);
        csr_src[p] = ei[e];
    }
}

// ---------------- fused weight prep ----------------
// fragment order: element (k,n): c=k>>6 (+cBase), s=(k>>5)&1, quad=(k>>3)&3, j=k&7,
// G=n>>4, l=quad*16+(n&15); dst=((((c*2+s)*8+G)*64)+l)*8+j

__device__ __forceinline__ void split_store(float x, size_t dst, short* hi, short* lo) {
    unsigned int ux = __builtin_bit_cast(unsigned int, x);
    unsigned short hx = (unsigned short)(ux >> 16);
    float fx = __builtin_bit_cast(float, ux & 0xffff0000u);
    unsigned short lx = (unsigned short)(__builtin_bit_cast(unsigned int, x - fx) >> 16);
    hi[dst] = (short)hx;
    lo[dst] = (short)lx;
}

__device__ __forceinline__ void prep_one(float x, int k, int n, int cBase,
                                         short* hi, short* lo) {
    int c = (k >> 6) + cBase;
    int s = (k >> 5) & 1, quad = (k >> 3) & 3, j = k & 7;
    int G = n >> 4, l = quad * 16 + (n & 15);
    size_t dst = ((((size_t)(c * 2 + s)) * 8 + G) * 64 + l) * 8 + j;
    split_store(x, dst, hi, lo);
}

__global__ void k_prep_all(const float* __restrict__ W1, const float* __restrict__ Wl,
                           const float* __restrict__ Wr, const float* __restrict__ W3,
                           const float* __restrict__ att_src, const float* __restrict__ att_dst,
                           short* __restrict__ w1hi, short* __restrict__ w1lo,
                           short* __restrict__ wshi, short* __restrict__ wslo,
                           short* __restrict__ w3hi, short* __restrict__ w3lo,
                           float* __restrict__ wsrc, float* __restrict__ wdst) {
    int b = blockIdx.x, tid = threadIdx.x;
    if (b < 64) {
        int i = b * 256 + tid;
        prep_one(W1[i], i >> 7, i & 127, 0, w1hi, w1lo);
    } else if (b < 128) {
        int i = (b - 64) * 256 + tid;
        prep_one(Wl[i], i >> 7, i & 127, 0, wshi, wslo);
    } else if (b < 192) {
        int i = (b - 128) * 256 + tid;
        prep_one(Wr[i], i >> 7, i & 127, 2, wshi, wslo);
    } else if (b < 384) {
        int i = (b - 192) * 256 + tid;  // 49152 total
        int k = i >> 7, n = i & 127;
        int h = k >> 7, kk = k & 127;
        float x = W3[(size_t)kk * 384 + h * 128 + n] * (1.f / 3.f);
        prep_one(x, k, n, 0, w3hi, w3lo);
    } else {
        for (int e = tid; e < 384; e += 256) {
            int h = e >> 7, k = e & 127;
            float s1 = 0.f, s2 = 0.f;
            const float* wrow = W3 + (size_t)k * 384 + h * 128;
            const float* as = att_src + h * 128;
            const float* ad = att_dst + h * 128;
            for (int j = 0; j < 128; j++) {
                float wv = wrow[j];
                s1 += wv * as[j];
                s2 += wv * ad[j];
            }
            wsrc[e] = s1;
            wdst[e] = s2;
        }
    }
}

// ---------------- MFMA GEMM  C = [A1|A2] @ B + bias  (+ optional BN stats) -------

template <bool ABF16, bool OUTB, bool STATS>
__global__ __launch_bounds__(256) void k_gemm_mfma(
    const void* __restrict__ A1v, const void* __restrict__ A2v,
    const short* __restrict__ Bhi, const short* __restrict__ Blo,
    const float* __restrict__ bias, void* __restrict__ Cv,
    float* __restrict__ sums, int M, int kc1, int kcT, int strideA1) {
    __shared__ short Ahi[128 * 72];
    __shared__ short Alo[ABF16 ? 8 : 128 * 72];
    __shared__ float cs[256];
    int tid = threadIdx.x;
    int rBase = blockIdx.x * 128;
    int wv = tid >> 6, lane = tid & 63;
    int rowHalf = wv >> 1, colHalf = wv & 1;
    int quad = lane >> 4, l15 = lane & 15;

    f32x4 acc[4][4];
#pragma unroll
    for (int a = 0; a < 4; a++)
#pragma unroll
        for (int b = 0; b < 4; b++) acc[a][b] = (f32x4)(0.f);

    for (int c = 0; c < kcT; c++) {
        const void* Asrc;
        int kOff, strideA;
        if (c < kc1) { Asrc = A1v; kOff = c * 64; strideA = strideA1; }
        else { Asrc = A2v; kOff = (c - kc1) * 64; strideA = 128; }

        __syncthreads();
        if (ABF16) {
            const unsigned short* As = (const unsigned short*)Asrc;
#pragma unroll
            for (int q = 0; q < 4; q++) {
                int slot = q * 256 + tid;
                int r = slot >> 3, k8 = slot & 7;
                uint4 v = make_uint4(0, 0, 0, 0);
                int gr = rBase + r;
                if (gr < M) v = *(const uint4*)(As + (size_t)gr * strideA + kOff + k8 * 8);
                *(uint4*)(Ahi + r * 72 + k8 * 8) = v;
            }
        } else {
            const float* As = (const float*)Asrc;
#pragma unroll
            for (int q8 = 0; q8 < 8; q8++) {
                int slot = q8 * 256 + tid;
                int r = slot >> 4, k4 = slot & 15;
                float4 v = make_float4(0.f, 0.f, 0.f, 0.f);
                int gr = rBase + r;
                if (gr < M) v = *(const float4*)(As + (size_t)gr * strideA + kOff + k4 * 4);
                unsigned int ux = __builtin_bit_cast(unsigned int, v.x);
                unsigned int uy = __builtin_bit_cast(unsigned int, v.y);
                unsigned int uz = __builtin_bit_cast(unsigned int, v.z);
                unsigned int uw = __builtin_bit_cast(unsigned int, v.w);
                unsigned int hx = ux >> 16, hy = uy >> 16, hz = uz >> 16, hw = uw >> 16;
                float fx = __builtin_bit_cast(float, ux & 0xffff0000u);
                float fy = __builtin_bit_cast(float, uy & 0xffff0000u);
                float fz = __builtin_bit_cast(float, uz & 0xffff0000u);
                float fw = __builtin_bit_cast(float, uw & 0xffff0000u);
                unsigned int lx = __builtin_bit_cast(unsigned int, v.x - fx) >> 16;
                unsigned int ly = __builtin_bit_cast(unsigned int, v.y - fy) >> 16;
                unsigned int lz = __builtin_bit_cast(unsigned int, v.z - fz) >> 16;
                unsigned int lw = __builtin_bit_cast(unsigned int, v.w - fw) >> 16;
                uint2 ph = make_uint2(hx | (hy << 16), hz | (hw << 16));
                uint2 pl = make_uint2(lx | (ly << 16), lz | (lw << 16));
                *(uint2*)(Ahi + r * 72 + k4 * 4) = ph;
                *(uint2*)(Alo + r * 72 + k4 * 4) = pl;
            }
        }
        __syncthreads();

#pragma unroll
        for (int s = 0; s < 2; s++) {
            short8 ah[4], al[4];
#pragma unroll
            for (int rb = 0; rb < 4; rb++) {
                int m = rowHalf * 64 + rb * 16 + l15;
                ah[rb] = *(const short8*)(Ahi + m * 72 + s * 32 + quad * 8);
                if (!ABF16) al[rb] = *(const short8*)(Alo + m * 72 + s * 32 + quad * 8);
            }
#pragma unroll
            for (int cg = 0; cg < 4; cg++) {
                int G = colHalf * 4 + cg;
                size_t bo = ((((size_t)(c * 2 + s)) * 8 + G) * 64 + lane) * 8;
                short8 bh = *(const short8*)(Bhi + bo);
                short8 bl = *(const short8*)(Blo + bo);
#pragma unroll
                for (int rb = 0; rb < 4; rb++) {
                    acc[rb][cg] = __builtin_amdgcn_mfma_f32_16x16x32_bf16(ah[rb], bh, acc[rb][cg], 0, 0, 0);
                    if (!ABF16)
                        acc[rb][cg] = __builtin_amdgcn_mfma_f32_16x16x32_bf16(al[rb], bh, acc[rb][cg], 0, 0, 0);
                    acc[rb][cg] = __builtin_amdgcn_mfma_f32_16x16x32_bf16(ah[rb], bl, acc[rb][cg], 0, 0, 0);
                }
            }
        }
    }

    if (STATS) {
        cs[tid] = 0.f;
        __syncthreads();
    }

#pragma unroll
    for (int cg = 0; cg < 4; cg++) {
        int col = colHalf * 64 + cg * 16 + l15;
        float bv = bias ? bias[col] : 0.f;
        float ps = 0.f, pq = 0.f;
#pragma unroll
        for (int rb = 0; rb < 4; rb++) {
#pragma unroll
            for (int r = 0; r < 4; r++) {
                int row = rBase + rowHalf * 64 + rb * 16 + quad * 4 + r;
                if (row < M) {
                    float ov = acc[rb][cg][r] + bv;
                    if (OUTB) ((unsigned short*)Cv)[(size_t)row * HH + col] = f2b(ov);
                    else ((float*)Cv)[(size_t)row * HH + col] = ov;
                    if (STATS) { ps += ov; pq += ov * ov; }
                }
            }
        }
        if (STATS) {
            ps += __shfl_xor(ps, 16, 64); ps += __shfl_xor(ps, 32, 64);
            pq += __shfl_xor(pq, 16, 64); pq += __shfl_xor(pq, 32, 64);
            if (quad == 0) {
                atomicAdd(&cs[col], ps);
                atomicAdd(&cs[128 + col], pq);
            }
        }
    }
    if (STATS) {
        __syncthreads();
        atomicAdd(&sums[tid], cs[tid]);
    }
}

// ---------------- GCN aggregation (8 nodes/wave, fused BN stats) ----------------

__global__ void k_gcn_agg(const unsigned int* __restrict__ hb, const int* __restrict__ row_start,
                          const int* __restrict__ deg, const int* __restrict__ csr,
                          const float* __restrict__ dinv, const float* __restrict__ b1,
                          float* __restrict__ out, float* __restrict__ sums) {
    __shared__ float ls[256];
    int tid = threadIdx.x;
    int wv = tid >> 6, lane = tid & 63;
    float2 bb = ((const float2*)b1)[lane];
    float2 sacc = make_float2(0.f, 0.f), qacc = make_float2(0.f, 0.f);
    int nBase = (blockIdx.x * 4 + wv) * 8;
    for (int k = 0; k < 8; k++) {
        int n = nBase + k;
        if (n >= NN) break;
        float di = dinv[n];
        float2 hv = b2f2(hb[(size_t)n * 64 + lane]);
        float wsq = di * di;
        float2 acc = make_float2(hv.x * wsq, hv.y * wsq);
        int s0 = row_start[n], cnt = deg[n];
        int i = 0;
        for (; i + 4 <= cnt; i += 4) {
            int ss[4]; float ww[4]; unsigned int vv[4];
#pragma unroll
            for (int j = 0; j < 4; j++) ss[j] = csr[s0 + i + j];
#pragma unroll
            for (int j = 0; j < 4; j++) { ww[j] = dinv[ss[j]]; vv[j] = hb[(size_t)ss[j] * 64 + lane]; }
#pragma unroll
            for (int j = 0; j < 4; j++) {
                float2 v = b2f2(vv[j]);
                float wj = ww[j] * di;
                acc.x += v.x * wj; acc.y += v.y * wj;
            }
        }
        for (; i < cnt; i++) {
            int s = csr[s0 + i];
            float wj = dinv[s] * di;
            float2 v = b2f2(hb[(size_t)s * 64 + lane]);
            acc.x += v.x * wj; acc.y += v.y * wj;
        }
        acc.x += bb.x; acc.y += bb.y;
        ((float2*)out)[(size_t)n * 64 + lane] = acc;
        sacc.x += acc.x; sacc.y += acc.y;
        qacc.x += acc.x * acc.x; qacc.y += acc.y * acc.y;
    }
    ls[tid] = 0.f;
    __syncthreads();
    atomicAdd(&ls[2 * lane], sacc.x);
    atomicAdd(&ls[2 * lane + 1], sacc.y);
    atomicAdd(&ls[128 + 2 * lane], qacc.x);
    atomicAdd(&ls[128 + 2 * lane + 1], qacc.y);
    __syncthreads();
    atomicAdd(&sums[tid], ls[tid]);
}

// ---------------- SAGE aggregation ----------------

__global__ void k_sage_agg(const unsigned int* __restrict__ hb, const int* __restrict__ row_start,
                           const int* __restrict__ deg, const int* __restrict__ csr,
                           const float* __restrict__ inv_sage, unsigned int* __restrict__ outb) {
    int n = blockIdx.x * 4 + (threadIdx.x >> 6);
    if (n >= NN) return;
    int lane = threadIdx.x & 63;
    float2 acc = make_float2(0.f, 0.f);
    int s0 = row_start[n], cnt = deg[n];
    int i = 0;
    for (; i + 4 <= cnt; i += 4) {
        int ss[4]; unsigned int vv[4];
#pragma unroll
        for (int j = 0; j < 4; j++) ss[j] = csr[s0 + i + j];
#pragma unroll
        for (int j = 0; j < 4; j++) vv[j] = hb[(size_t)ss[j] * 64 + lane];
#pragma unroll
        for (int j = 0; j < 4; j++) {
            float2 v = b2f2(vv[j]);
            acc.x += v.x; acc.y += v.y;
        }
    }
    for (; i < cnt; i++) {
        float2 v = b2f2(hb[(size_t)csr[s0 + i] * 64 + lane]);
        acc.x += v.x; acc.y += v.y;
    }
    float sc = inv_sage[n];
    outb[(size_t)n * 64 + lane] = pack2(acc.x * sc, acc.y * sc);
}

// ---------------- GAT: fused per-node softmax + aggregation ----------------

__device__ __forceinline__ float lrelu(float a) { return fmaxf(a, SLOPE * a); }

__global__ void k_gat_fused(const unsigned int* __restrict__ hb, const int* __restrict__ row_start,
                            const int* __restrict__ deg, const int* __restrict__ csr,
                            const float4* __restrict__ asrc4, const float4* __restrict__ adst4,
                            float4* __restrict__ alphaE, unsigned int* __restrict__ aggb) {
    int n = blockIdx.x * 4 + (threadIdx.x >> 6);
    if (n >= NN) return;
    int lane = threadIdx.x & 63;
    float4 ad = adst4[n], asv = asrc4[n];
    float es0 = lrelu(asv.x + ad.x), es1 = lrelu(asv.y + ad.y), es2 = lrelu(asv.z + ad.z);
    int s0 = row_start[n], cnt = deg[n];
    float self0, self1, self2;
    float al0 = 0.f, al1 = 0.f, al2 = 0.f;
    int sReg = 0;
    bool fast = (cnt <= 64);
    if (fast) {
        bool valid = lane < cnt;
        float e0 = -3e38f, e1 = -3e38f, e2 = -3e38f;
        if (valid) {
            sReg = csr[s0 + lane];
            float4 a4 = asrc4[sReg];
            e0 = lrelu(a4.x + ad.x); e1 = lrelu(a4.y + ad.y); e2 = lrelu(a4.z + ad.z);
        }
        float M0 = e0, M1 = e1, M2 = e2;
#pragma unroll
        for (int o = 32; o > 0; o >>= 1) {
            M0 = fmaxf(M0, __shfl_xor(M0, o, 64));
            M1 = fmaxf(M1, __shfl_xor(M1, o, 64));
            M2 = fmaxf(M2, __shfl_xor(M2, o, 64));
        }
        float m0 = fmaxf(es0, M0), m1 = fmaxf(es1, M1), m2 = fmaxf(es2, M2);
        float w0 = valid ? __expf(e0 - m0) : 0.f;
        float w1 = valid ? __expf(e1 - m1) : 0.f;
        float w2 = valid ? __expf(e2 - m2) : 0.f;
        float S0 = w0, S1 = w1, S2 = w2;
#pragma unroll
        for (int o = 32; o > 0; o >>= 1) {
            S0 += __shfl_xor(S0, o, 64);
            S1 += __shfl_xor(S1, o, 64);
            S2 += __shfl_xor(S2, o, 64);
        }
        float sw0 = __expf(es0 - m0), sw1 = __expf(es1 - m1), sw2 = __expf(es2 - m2);
        float r0 = 1.f / (S0 + sw0), r1 = 1.f / (S1 + sw1), r2 = 1.f / (S2 + sw2);
        al0 = w0 * r0; al1 = w1 * r1; al2 = w2 * r2;
        self0 = sw0 * r0; self1 = sw1 * r1; self2 = sw2 * r2;
    } else {
        float m0 = es0, m1 = es1, m2 = es2;
        for (int base = 0; base < cnt; base += 64) {
            int i2 = base + lane;
            float e0 = -3e38f, e1 = -3e38f, e2 = -3e38f;
            if (i2 < cnt) {
                int s = csr[s0 + i2];
                float4 a4 = asrc4[s];
                e0 = lrelu(a4.x + ad.x); e1 = lrelu(a4.y + ad.y); e2 = lrelu(a4.z + ad.z);
                alphaE[s0 + i2] = make_float4(e0, e1, e2, 0.f);
            }
#pragma unroll
            for (int o = 32; o > 0; o >>= 1) {
                e0 = fmaxf(e0, __shfl_xor(e0, o, 64));
                e1 = fmaxf(e1, __shfl_xor(e1, o, 64));
                e2 = fmaxf(e2, __shfl_xor(e2, o, 64));
            }
            m0 = fmaxf(m0, e0); m1 = fmaxf(m1, e1); m2 = fmaxf(m2, e2);
        }
        float l0 = __expf(es0 - m0), l1 = __expf(es1 - m1), l2 = __expf(es2 - m2);
        for (int base = 0; base < cnt; base += 64) {
            int i2 = base + lane;
            float w0 = 0.f, w1 = 0.f, w2 = 0.f;
            if (i2 < cnt) {
                float4 e = alphaE[s0 + i2];
                w0 = __expf(e.x - m0); w1 = __expf(e.y - m1); w2 = __expf(e.z - m2);
            }
#pragma unroll
            for (int o = 32; o > 0; o >>= 1) {
                w0 += __shfl_xor(w0, o, 64);
                w1 += __shfl_xor(w1, o, 64);
                w2 += __shfl_xor(w2, o, 64);
            }
            l0 += w0; l1 += w1; l2 += w2;
        }
        float r0 = 1.f / l0, r1 = 1.f / l1, r2 = 1.f / l2;
        self0 = __expf(es0 - m0) * r0;
        self1 = __expf(es1 - m1) * r1;
        self2 = __expf(es2 - m2) * r2;
        for (int base = 0; base < cnt; base += 64) {
            int i2 = base + lane;
            if (i2 < cnt) {
                float4 e = alphaE[s0 + i2];
                alphaE[s0 + i2] = make_float4(__expf(e.x - m0) * r0, __expf(e.y - m1) * r1,
                                              __expf(e.z - m2) * r2, 0.f);
            }
        }
    }

    // phase 2: feature aggregation
    float2 hv = b2f2(hb[(size_t)n * 64 + lane]);
    float2 a0 = make_float2(hv.x * self0, hv.y * self0);
    float2 a1 = make_float2(hv.x * self1, hv.y * self1);
    float2 a2 = make_float2(hv.x * self2, hv.y * self2);
    if (fast) {
        int i = 0;
        for (; i + 4 <= cnt; i += 4) {
            int ss[4]; unsigned int vv[4]; float aa0[4], aa1[4], aa2[4];
#pragma unroll
            for (int j = 0; j < 4; j++) {
                ss[j] = __shfl(sReg, i + j, 64);
                aa0[j] = __shfl(al0, i + j, 64);
                aa1[j] = __shfl(al1, i + j, 64);
                aa2[j] = __shfl(al2, i + j, 64);
            }
#pragma unroll
            for (int j = 0; j < 4; j++) vv[j] = hb[(size_t)ss[j] * 64 + lane];
#pragma unroll
            for (int j = 0; j < 4; j++) {
                float2 v = b2f2(vv[j]);
                a0.x += aa0[j] * v.x; a0.y += aa0[j] * v.y;
                a1.x += aa1[j] * v.x; a1.y += aa1[j] * v.y;
                a2.x += aa2[j] * v.x; a2.y += aa2[j] * v.y;
            }
        }
        for (; i < cnt; i++) {
            int s = __shfl(sReg, i, 64);
            float w0 = __shfl(al0, i, 64), w1 = __shfl(al1, i, 64), w2 = __shfl(al2, i, 64);
            float2 v = b2f2(hb[(size_t)s * 64 + lane]);
            a0.x += w0 * v.x; a0.y += w0 * v.y;
            a1.x += w1 * v.x; a1.y += w1 * v.y;
            a2.x += w2 * v.x; a2.y += w2 * v.y;
        }
    } else {
        for (int i = 0; i < cnt; i++) {
            int s = csr[s0 + i];
            float4 al = alphaE[s0 + i];
            float2 v = b2f2(hb[(size_t)s * 64 + lane]);
            a0.x += al.x * v.x; a0.y += al.x * v.y;
            a1.x += al.y * v.x; a1.y += al.y * v.y;
            a2.x += al.z * v.x; a2.y += al.z * v.y;
        }
    }
    unsigned int* op = aggb + (size_t)n * 192;
    op[lane] = pack2(a0.x, a0.y);
    op[64 + lane] = pack2(a1.x, a1.y);
    op[128 + lane] = pack2(a2.x, a2.y);
}

// ---------------- BatchNorm + ELU (bf16-out only) ----------------

__device__ __forceinline__ float elu1(float x) { return x > 0.f ? x : (__expf(x) - 1.f); }

__device__ __forceinline__ float4 bn_apply4(float4 v, const float* sums,
                                            const float* gamma, const float* beta, int f4) {
    const float invN = 1.0f / NN;
    float4 s4 = *(const float4*)(sums + f4);
    float4 q4 = *(const float4*)(sums + 128 + f4);
    float4 g4 = *(const float4*)(gamma + f4);
    float4 b4 = *(const float4*)(beta + f4);
    float mx = s4.x * invN, my = s4.y * invN, mz = s4.z * invN, mw = s4.w * invN;
    float scx = rsqrtf(q4.x * invN - mx * mx + EPSV) * g4.x;
    float scy = rsqrtf(q4.y * invN - my * my + EPSV) * g4.y;
    float scz = rsqrtf(q4.z * invN - mz * mz + EPSV) * g4.z;
    float scw = rsqrtf(q4.w * invN - mw * mw + EPSV) * g4.w;
    v.x = elu1(v.x * scx + (b4.x - mx * scx));
    v.y = elu1(v.y * scy + (b4.y - my * scy));
    v.z = elu1(v.z * scz + (b4.z - mz * scz));
    v.w = elu1(v.w * scw + (b4.w - mw * scw));
    return v;
}

__global__ void k_bn_elu(const float* __restrict__ h, const float* __restrict__ sums,
                         const float* __restrict__ gamma, const float* __restrict__ beta,
                         unsigned int* __restrict__ hb) {
    int i = blockIdx.x * 256 + threadIdx.x;  // NN*32
    int f4 = (i & 31) << 2;
    float4 v = bn_apply4(((const float4*)h)[i], sums, gamma, beta, f4);
    uint2 p = make_uint2(pack2(v.x, v.y), pack2(v.z, v.w));
    *(uint2*)(hb + ((size_t)(i >> 5)) * 64 + (i & 31) * 2) = p;
}

__global__ void k_bn_elu_att(const float* __restrict__ h, const float* __restrict__ sums,
                             const float* __restrict__ gamma, const float* __restrict__ beta,
                             const float* __restrict__ wsrc, const float* __restrict__ wdst,
                             unsigned int* __restrict__ hb, float4* __restrict__ asrc4,
                             float4* __restrict__ adst4) {
    int i = blockIdx.x * 256 + threadIdx.x;
    int fi = i & 31;
    int f4 = fi << 2;
    float4 v = bn_apply4(((const float4*)h)[i], sums, gamma, beta, f4);
    uint2 p = make_uint2(pack2(v.x, v.y), pack2(v.z, v.w));
    *(uint2*)(hb + ((size_t)(i >> 5)) * 64 + fi * 2) = p;
    const float4* ws4 = (const float4*)wsrc;
    const float4* wd4 = (const float4*)wdst;
    float d[6];
#pragma unroll
    for (int hd = 0; hd < 3; hd++) {
        float4 a = ws4[hd * 32 + fi];
        float4 b = wd4[hd * 32 + fi];
        d[hd] = v.x * a.x + v.y * a.y + v.z * a.z + v.w * a.w;
        d[3 + hd] = v.x * b.x + v.y * b.y + v.z * b.z + v.w * b.w;
    }
#pragma unroll
    for (int o = 16; o > 0; o >>= 1) {
#pragma unroll
        for (int j = 0; j < 6; j++) d[j] += __shfl_xor(d[j], o, 64);
    }
    if ((threadIdx.x & 31) == 0) {
        int r = i >> 5;
        asrc4[r] = make_float4(d[0], d[1], d[2], 0.f);
        adst4[r] = make_float4(d[3], d[4], d[5], 0.f);
    }
}

// ---------------- Pool (BN+ELU fused) + classifier ----------------

#define POOL_BLOCKS 800

__global__ void k_pool_bn(const float* __restrict__ h, const int* __restrict__ batch,
                          const float* __restrict__ sums, const float* __restrict__ gamma,
                          const float* __restrict__ beta, float* __restrict__ pool,
                          float* __restrict__ cntf) {
    const int RP = (NN + POOL_BLOCKS - 1) / POOL_BLOCKS;
    int r0 = blockIdx.x * RP;
    int r1 = r0 + RP;
    if (r1 > NN) r1 = NN;
    if (r0 >= r1) return;
    int f = threadIdx.x;
    const float invN = 1.0f / NN;
    float mu = sums[f] * invN;
    float var = sums[128 + f] * invN - mu * mu;
    float sc = rsqrtf(var + EPSV) * gamma[f];
    float sh = beta[f] - mu * sc;
    int g = batch[r0];
    float s = 0.f, c = 0.f;
    for (int r = r0; r < r1; r++) {
        int gr = batch[r];
        if (gr != g) {
            atomicAdd(&pool[g * 128 + f], s);
            if (f == 0) atomicAdd(&cntf[g], c);
            s = 0.f; c = 0.f; g = gr;
        }
        s += elu1(h[(size_t)r * 128 + f] * sc + sh);
        c += 1.f;
    }
    atomicAdd(&pool[g * 128 + f], s);
    if (f == 0) atomicAdd(&cntf[g], c);
}

__global__ void k_pool_fin(const float* __restrict__ pool, const float* __restrict__ cntf,
                           const float* __restrict__ Wc, const float* __restrict__ bc,
                           float* __restrict__ outp) {
    __shared__ float pr[128];
    int g = blockIdx.x, f = threadIdx.x;  // 128 threads
    float c = fmaxf(cntf[g], 1.f);
    float pv = pool[g * 128 + f] / c;
    outp[g * 128 + f] = pv;
    pr[f] = pv;
    __syncthreads();
    if (f < CC) {
        float s = bc[f];
        for (int k = 0; k < 128; k++) s += pr[k] * Wc[k * CC + f];
        outp[GG * HH + g * CC + f] = s;
    }
}

// ---------------- launch ----------------

extern "C" void kernel_launch(void* const* d_in, const int* in_sizes, int n_in,
                              void* d_out, int out_size, void* d_ws, size_t ws_size,
                              hipStream_t stream) {
    const float* x = (const float*)d_in[0];
    const int* ei = (const int*)d_in[1];
    const int* batch = (const int*)d_in[2];
    const float* W1 = (const float*)d_in[3];
    const float* b1 = (const float*)d_in[4];
    const float* gamma1 = (const float*)d_in[5];
    const float* beta1 = (const float*)d_in[6];
    const float* Wl = (const float*)d_in[7];
    const float* bl = (const float*)d_in[8];
    const float* Wr = (const float*)d_in[9];
    const float* gamma2 = (const float*)d_in[10];
    const float* beta2 = (const float*)d_in[11];
    const float* W3 = (const float*)d_in[12];
    const float* att_src = (const float*)d_in[13];
    const float* att_dst = (const float*)d_in[14];
    const float* b3 = (const float*)d_in[15];
    const float* gamma3 = (const float*)d_in[16];
    const float* beta3 = (const float*)d_in[17];
    const float* Wc = (const float*)d_in[18];
    const float* bc = (const float*)d_in[19];

    char* w = (char*)d_ws;
    size_t o = 0;
    float* bufA = (float*)(w + o); o += (size_t)NN * 128 * 4;   // fp32 (gcn out / gemm3 out)
    float* bufC = (float*)(w + o); o += (size_t)NN * 128 * 4;   // fp32 gemm2 out
    unsigned int* h0b = (unsigned int*)(w + o); o += (size_t)NN * 128 * 2;
    unsigned int* h1b = (unsigned int*)(w + o); o += (size_t)NN * 128 * 2;
    unsigned int* sageb = (unsigned int*)(w + o); o += (size_t)NN * 128 * 2;
    unsigned int* h2b = (unsigned int*)(w + o); o += (size_t)NN * 128 * 2;
    unsigned int* aggDb = (unsigned int*)(w + o); o += (size_t)NN * 384 * 2;
    int* csr = (int*)(w + o); o += (size_t)EE * 4;
    int* deg = (int*)(w + o); o += (size_t)NN * 4;
    int* row_start = (int*)(w + o); o += (size_t)NN * 4;
    int* cursor = (int*)(w + o); o += (size_t)NN * 4;
    float* dinv = (float*)(w + o); o += (size_t)NN * 4;
    float* inv_sage = (float*)(w + o); o += (size_t)NN * 4;
    float4* asrc4 = (float4*)(w + o); o += (size_t)NN * 16;
    float4* adst4 = (float4*)(w + o); o += (size_t)NN * 16;
    float* bn_sums = (float*)(w + o); o += 3 * 256 * 4;
    int* blk = (int*)(w + o); o += 1024;
    float* poolacc = (float*)(w + o); o += (size_t)GG * 128 * 4;
    float* cntf = (float*)(w + o); o += (size_t)GG * 4;   // contiguous after poolacc
    float* wsrc = (float*)(w + o); o += 384 * 4;
    float* wdst = (float*)(w + o); o += 384 * 4;
    float4* alphaE = (float4*)(w + o); o += (size_t)EE * 16;  // slow-path scratch
    short* w1hi = (short*)(w + o); o += (size_t)128 * 128 * 2;
    short* w1lo = (short*)(w + o); o += (size_t)128 * 128 * 2;
    short* wshi = (short*)(w + o); o += (size_t)256 * 128 * 2;
    short* wslo = (short*)(w + o); o += (size_t)256 * 128 * 2;
    short* w3hi = (short*)(w + o); o += (size_t)384 * 128 * 2;
    short* w3lo = (short*)(w + o); o += (size_t)384 * 128 * 2;

    float* outp = (float*)d_out;

    const int NB_SCAN = (NN + 255) / 256;   // 196
    const int EB = (EE + 255) / 256;
    const int NW4 = (NN + 3) / 4;           // 1 node/wave kernels
    const int NW32 = (NN + 31) / 32;        // 8 nodes/wave (gcn)
    const int GB = (NN + 127) / 128;        // 391

    k_zero<<<NB_SCAN, 256, 0, stream>>>(deg, bn_sums, poolacc);
    k_count_deg<<<EB, 256, 0, stream>>>(ei, deg);
    k_scan1<<<NB_SCAN, 256, 0, stream>>>(deg, row_start, blk);
    k_scan2<<<1, 256, 0, stream>>>(blk, NB_SCAN);
    k_scan3<<<NB_SCAN, 256, 0, stream>>>(row_start, blk, deg, cursor, dinv, inv_sage);
    k_fill<<<EB, 256, 0, stream>>>(ei, cursor, csr);
    k_prep_all<<<385, 256, 0, stream>>>(W1, Wl, Wr, W3, att_src, att_dst, w1hi, w1lo,
                                        wshi, wslo, w3hi, w3lo, wsrc, wdst);

    // Layer 1: GCN
    k_gemm_mfma<false, true, false><<<GB, 256, 0, stream>>>(x, nullptr, w1hi, w1lo, nullptr,
                                                            h0b, nullptr, NN, 2, 2, 128);
    k_gcn_agg<<<NW32, 256, 0, stream>>>(h0b, row_start, deg, csr, dinv, b1, bufA, bn_sums);
    k_bn_elu<<<NN * 32 / 256, 256, 0, stream>>>(bufA, bn_sums, gamma1, beta1, h1b);

    // Layer 2: SAGE (fused K=256: [sage_agg | h1] @ [Wl; Wr] + bl, stats in epilogue)
    k_sage_agg<<<NW4, 256, 0, stream>>>(h1b, row_start, deg, csr, inv_sage, sageb);
    k_gemm_mfma<true, false, true><<<GB, 256, 0, stream>>>(sageb, h1b, wshi, wslo, bl, bufC,
                                                           bn_sums + 256, NN, 2, 4, 128);
    k_bn_elu_att<<<NN * 32 / 256, 256, 0, stream>>>(bufC, bn_sums + 256, gamma2, beta2,
                                                    wsrc, wdst, h2b, asrc4, adst4);

    // Layer 3: GAT (fused softmax+agg, stats in GEMM epilogue, BN+ELU in pool)
    k_gat_fused<<<NW4, 256, 0, stream>>>(h2b, row_start, deg, csr, asrc4, adst4, alphaE, aggDb);
    k_gemm_mfma<true, false, true><<<GB, 256, 0, stream>>>(aggDb, nullptr, w3hi, w3lo, b3, bufA,
                                                           bn_sums + 512, NN, 6, 6, 384);

    // Pool (BN+ELU inline) + classifier
    k_pool_bn<<<POOL_BLOCKS, 128, 0, stream>>>(bufA, batch, bn_sums + 512, gamma3, beta3,
                                               poolacc, cntf);
    k_pool_fin<<<GG, 128, 0, stream>>>(poolacc, cntf, Wc, bc, outp);
}